// Round 2
// baseline (513.849 us; speedup 1.0000x reference)
//
#include <hip/hip_runtime.h>

// ---------------------------------------------------------------------------
// PointNet2-AT inference pipeline, bf16 MFMA GEMMs + fp32 epilogues.
// B=16, N=4096 -> M = 65536 rows everywhere.
// R1: workspace overlaid by live-range (peak ~195MB, was 286MB — suspected
//     ws overflow caused the R0 crash); hipMemsetAsync -> zero kernel.
// ---------------------------------------------------------------------------

#define M_ROWS 65536
#define MB ((size_t)1 << 20)

typedef __bf16 bf16x8 __attribute__((ext_vector_type(8)));
typedef float floatx4 __attribute__((ext_vector_type(4)));

__device__ __forceinline__ float b2f(ushort u) {
    unsigned int x = ((unsigned int)u) << 16;
    float f;
    __builtin_memcpy(&f, &x, 4);
    return f;
}
__device__ __forceinline__ ushort f2bf(float f) {
    unsigned int x;
    __builtin_memcpy(&x, &f, 4);
    unsigned int r = x + 0x7fffu + ((x >> 16) & 1u);  // RNE
    return (ushort)(r >> 16);
}
__device__ __forceinline__ float lo16(unsigned u) { return b2f((ushort)(u & 0xffffu)); }
__device__ __forceinline__ float hi16(unsigned u) { return b2f((ushort)(u >> 16)); }

// ---------------------------------------------------------------------------
// Prep: transpose+convert weights fp32[K,N] -> bf16 Wt[N,Kp] (zero-padded K),
// and fold BN params into scale/shift arrays.
// ---------------------------------------------------------------------------
struct PrepArgs {
    const float* wsrc[5]; ushort* wdst[5]; int wK[5], wN[5], wKp[5], wcount[5];
    const float* g[5]; const float* bb[5]; const float* mm[5]; const float* vv[5];
    float* sc[5]; float* sh[5]; int C[5];
};

__global__ __launch_bounds__(256) void prep_kernel(PrepArgs p, int totalW, int totalC) {
    int idx = blockIdx.x * 256 + threadIdx.x;
    if (idx < totalW) {
        int s = 0, base = 0;
        for (s = 0; s < 5; ++s) {
            if (idx < base + p.wcount[s]) break;
            base += p.wcount[s];
        }
        int local = idx - base;
        int n = local / p.wKp[s];
        int k = local - n * p.wKp[s];
        p.wdst[s][local] = (k < p.wK[s]) ? f2bf(p.wsrc[s][k * p.wN[s] + n]) : (ushort)0;
    } else {
        int cidx = idx - totalW;
        if (cidx < totalC) {
            int s = 0, base = 0;
            for (s = 0; s < 5; ++s) {
                if (cidx < base + p.C[s]) break;
                base += p.C[s];
            }
            int c = cidx - base;
            float scv = p.g[s][c] * rsqrtf(p.vv[s][c] + 1e-5f);
            p.sc[s][c] = scv;
            p.sh[s][c] = p.bb[s][c] - p.mm[s][c] * scv;
        }
    }
}

__global__ __launch_bounds__(256) void zero_kernel(float* __restrict__ p, int n) {
    int i = blockIdx.x * 256 + threadIdx.x;
    if (i < n) p[i] = 0.0f;
}

// ---------------------------------------------------------------------------
// Layer 1: [M,6] @ [6,64] + BN + ReLU -> bf16 [M,64].  (K=6: vector kernel)
// block = 256 = 4 rows x 64 cols
// ---------------------------------------------------------------------------
__global__ __launch_bounds__(256) void l1_kernel(
    const float* __restrict__ xyz, const float* __restrict__ pts,
    const float* __restrict__ w1, const float* __restrict__ g,
    const float* __restrict__ b, const float* __restrict__ m,
    const float* __restrict__ v, ushort* __restrict__ f1) {
    __shared__ float w[384];
    __shared__ float sc[64], sh[64];
    int tid = threadIdx.x;
    if (tid < 64) {
        float s = g[tid] * rsqrtf(v[tid] + 1e-5f);
        sc[tid] = s;
        sh[tid] = b[tid] - m[tid] * s;
    }
    for (int i = tid; i < 384; i += 256) w[i] = w1[i];
    __syncthreads();
    int r = blockIdx.x * 4 + (tid >> 6);
    int c = tid & 63;
    float x0 = xyz[r * 3], x1 = xyz[r * 3 + 1], x2 = xyz[r * 3 + 2];
    float p0 = pts[r * 3], p1 = pts[r * 3 + 1], p2 = pts[r * 3 + 2];
    float a = x0 * w[c] + x1 * w[64 + c] + x2 * w[128 + c] +
              p0 * w[192 + c] + p1 * w[256 + c] + p2 * w[320 + c];
    a = fmaxf(a * sc[c] + sh[c], 0.0f);
    f1[(size_t)r * 64 + c] = f2bf(a);
}

// ---------------------------------------------------------------------------
// GEMM: C[M,N] = ReLU(BN(A[M,K] @ W[K,N])), A bf16 row-major (lda=K),
// Wt bf16 [N,K] row-major (pre-transposed). M%128==0, N%128==0, K%32==0.
// 128x128 block tile, 4 waves, each wave 64x64 via 4x4 MFMA 16x16x32 tiles.
// ---------------------------------------------------------------------------
#define BKP 40  // 32 + 8 pad (keeps 16B alignment, breaks bank aliasing)

__global__ __launch_bounds__(256) void gemm_bn_relu(
    const ushort* __restrict__ A, const ushort* __restrict__ Wt,
    const float* __restrict__ scale, const float* __restrict__ shift,
    ushort* __restrict__ C, int N, int K) {
    __shared__ ushort As[128 * BKP];
    __shared__ ushort Bs[128 * BKP];
    const int tid = threadIdx.x;
    const int bm0 = blockIdx.x * 128;
    const int bn0 = blockIdx.y * 128;
    const int wid = tid >> 6, ln = tid & 63;
    const int wr = wid >> 1, wc = wid & 1;
    const int lm = ln & 15, q = ln >> 4;

    floatx4 acc[4][4];
#pragma unroll
    for (int i = 0; i < 4; ++i)
#pragma unroll
        for (int j = 0; j < 4; ++j) acc[i][j] = (floatx4){0.f, 0.f, 0.f, 0.f};

    for (int kt = 0; kt < K; kt += 32) {
#pragma unroll
        for (int l = 0; l < 2; ++l) {
            int e = tid + 256 * l;
            int row = e >> 2;
            int kc = (e & 3) << 3;
            *(uint4*)(&As[row * BKP + kc]) =
                *(const uint4*)(&A[(size_t)(bm0 + row) * K + kt + kc]);
            *(uint4*)(&Bs[row * BKP + kc]) =
                *(const uint4*)(&Wt[(size_t)(bn0 + row) * K + kt + kc]);
        }
        __syncthreads();
        bf16x8 af[4], bf[4];
#pragma unroll
        for (int i = 0; i < 4; ++i)
            af[i] = *(const bf16x8*)(&As[(wr * 64 + i * 16 + lm) * BKP + q * 8]);
#pragma unroll
        for (int i = 0; i < 4; ++i)
            bf[i] = *(const bf16x8*)(&Bs[(wc * 64 + i * 16 + lm) * BKP + q * 8]);
#pragma unroll
        for (int mi = 0; mi < 4; ++mi)
#pragma unroll
            for (int ni = 0; ni < 4; ++ni)
                acc[mi][ni] = __builtin_amdgcn_mfma_f32_16x16x32_bf16(
                    af[mi], bf[ni], acc[mi][ni], 0, 0, 0);
        __syncthreads();
    }

#pragma unroll
    for (int mi = 0; mi < 4; ++mi) {
        int grow0 = bm0 + wr * 64 + mi * 16 + q * 4;
#pragma unroll
        for (int ni = 0; ni < 4; ++ni) {
            int gcol = bn0 + wc * 64 + ni * 16 + lm;
            float s = scale[gcol], t = shift[gcol];
#pragma unroll
            for (int r = 0; r < 4; ++r) {
                float val = acc[mi][ni][r] * s + t;
                val = fmaxf(val, 0.0f);
                C[(size_t)(grow0 + r) * N + gcol] = f2bf(val);
            }
        }
    }
}

// ---------------------------------------------------------------------------
// Gate: s = sigmoid(f3 . att_w + att_b); G = [bf16(xyz), f3*s, zeros] [M,288]
// one wave per row
// ---------------------------------------------------------------------------
__global__ __launch_bounds__(256) void gate_kernel(
    const ushort* __restrict__ f3, const float* __restrict__ attw,
    const float* __restrict__ attb, const float* __restrict__ xyz,
    ushort* __restrict__ G) {
    int tid = threadIdx.x;
    int ln = tid & 63, wid = tid >> 6;
    int r = blockIdx.x * 4 + wid;
    ushort4 fv = *(const ushort4*)&f3[(size_t)r * 256 + ln * 4];
    float f0 = b2f(fv.x), f1 = b2f(fv.y), f2 = b2f(fv.z), f3v = b2f(fv.w);
    float4 aw = *(const float4*)&attw[ln * 4];
    float sum = f0 * aw.x + f1 * aw.y + f2 * aw.z + f3v * aw.w;
#pragma unroll
    for (int o = 32; o > 0; o >>= 1) sum += __shfl_xor(sum, o);
    float s = 1.0f / (1.0f + expf(-(sum + attb[0])));
    size_t gb = (size_t)r * 288;
    G[gb + 3 + ln * 4 + 0] = f2bf(f0 * s);
    G[gb + 3 + ln * 4 + 1] = f2bf(f1 * s);
    G[gb + 3 + ln * 4 + 2] = f2bf(f2 * s);
    G[gb + 3 + ln * 4 + 3] = f2bf(f3v * s);
    if (ln < 3) G[gb + ln] = f2bf(xyz[r * 3 + ln]);
    if (ln >= 3 && ln < 32) G[gb + 256 + ln] = 0;  // cols 259..287 zero pad
}

// ---------------------------------------------------------------------------
// Logits: logits[r] = g3[r,:] . att_w   (one wave per row, K=1024)
// ---------------------------------------------------------------------------
__global__ __launch_bounds__(256) void logits_kernel(
    const ushort* __restrict__ g3, const float* __restrict__ attw,
    float* __restrict__ logits) {
    __shared__ float aw[1024];
    int tid = threadIdx.x;
    for (int i = tid; i < 1024; i += 256) aw[i] = attw[i];
    __syncthreads();
    int ln = tid & 63, wid = tid >> 6;
    int r = blockIdx.x * 4 + wid;
    const ushort* row = g3 + (size_t)r * 1024;
    float sum = 0.0f;
#pragma unroll
    for (int u = 0; u < 2; ++u) {
        int c0 = ln * 16 + u * 8;
        uint4 pk = *(const uint4*)&row[c0];
        sum += lo16(pk.x) * aw[c0] + hi16(pk.x) * aw[c0 + 1] +
               lo16(pk.y) * aw[c0 + 2] + hi16(pk.y) * aw[c0 + 3] +
               lo16(pk.z) * aw[c0 + 4] + hi16(pk.z) * aw[c0 + 5] +
               lo16(pk.w) * aw[c0 + 6] + hi16(pk.w) * aw[c0 + 7];
    }
#pragma unroll
    for (int o = 32; o > 0; o >>= 1) sum += __shfl_xor(sum, o);
    if (ln == 0) logits[r] = sum;
}

// ---------------------------------------------------------------------------
// Softmax over N=4096 per batch; one block of 1024 per batch.
// ---------------------------------------------------------------------------
__global__ __launch_bounds__(1024) void softmax_kernel(
    const float* __restrict__ logits, float* __restrict__ alpha) {
    __shared__ float red[1024];
    int b = blockIdx.x, t = threadIdx.x;
    float4 v = *(const float4*)&logits[b * 4096 + t * 4];
    float mx = fmaxf(fmaxf(v.x, v.y), fmaxf(v.z, v.w));
    red[t] = mx;
    __syncthreads();
    for (int s = 512; s > 0; s >>= 1) {
        if (t < s) red[t] = fmaxf(red[t], red[t + s]);
        __syncthreads();
    }
    float M = red[0];
    __syncthreads();
    float e0 = expf(v.x - M), e1 = expf(v.y - M), e2 = expf(v.z - M), e3 = expf(v.w - M);
    red[t] = e0 + e1 + e2 + e3;
    __syncthreads();
    for (int s = 512; s > 0; s >>= 1) {
        if (t < s) red[t] += red[t + s];
        __syncthreads();
    }
    float inv = 1.0f / red[0];
    *(float4*)&alpha[b * 4096 + t * 4] = make_float4(e0 * inv, e1 * inv, e2 * inv, e3 * inv);
}

// ---------------------------------------------------------------------------
// Pool: pooled[b,c] = sum_n alpha[b,n] * g3[b,n,c]; grid (4 cchunk, 16 b, 8 nsplit)
// ---------------------------------------------------------------------------
__global__ __launch_bounds__(256) void pool_kernel(
    const ushort* __restrict__ g3, const float* __restrict__ alpha,
    float* __restrict__ pooled) {
    int c = blockIdx.x * 256 + threadIdx.x;
    int b = blockIdx.y;
    int n0 = blockIdx.z * 512;
    const ushort* base = g3 + ((size_t)b * 4096 + n0) * 1024 + c;
    const float* al = alpha + b * 4096 + n0;
    float acc = 0.0f;
#pragma unroll 4
    for (int n = 0; n < 512; ++n) acc += al[n] * b2f(base[(size_t)n * 1024]);
    atomicAdd(&pooled[b * 1024 + c], acc);
}

// ---------------------------------------------------------------------------
// Head
// ---------------------------------------------------------------------------
__global__ __launch_bounds__(256) void head1_kernel(
    const float* __restrict__ pooled, const float* __restrict__ w,
    const float* __restrict__ g, const float* __restrict__ bb,
    const float* __restrict__ m, const float* __restrict__ v,
    float* __restrict__ h1) {
    int idx = blockIdx.x * 256 + threadIdx.x;  // 16*512
    int b = idx >> 9, c = idx & 511;
    float sc = g[c] * rsqrtf(v[c] + 1e-5f);
    float sh = bb[c] - m[c] * sc;
    const float* pr = pooled + b * 1024;
    float acc = 0.0f;
    for (int k = 0; k < 1024; ++k) acc += pr[k] * w[k * 512 + c];
    h1[idx] = fmaxf(acc * sc + sh, 0.0f);
}

__global__ __launch_bounds__(256) void head2_kernel(
    const float* __restrict__ h1, const float* __restrict__ w,
    const float* __restrict__ g, const float* __restrict__ bb,
    const float* __restrict__ m, const float* __restrict__ v,
    float* __restrict__ h2) {
    int b = blockIdx.x, c = threadIdx.x;  // 16 x 256
    float sc = g[c] * rsqrtf(v[c] + 1e-5f);
    float sh = bb[c] - m[c] * sc;
    const float* hr = h1 + b * 512;
    float acc = 0.0f;
    for (int k = 0; k < 512; ++k) acc += hr[k] * w[k * 256 + c];
    h2[b * 256 + c] = fmaxf(acc * sc + sh, 0.0f);
}

__global__ __launch_bounds__(64) void head3_kernel(
    const float* __restrict__ h2, const float* __restrict__ pw,
    const float* __restrict__ pb, float* __restrict__ out) {
    int b = blockIdx.x, ln = threadIdx.x;
    float4 hv = *(const float4*)&h2[b * 256 + ln * 4];
    float4 wv = *(const float4*)&pw[ln * 4];
    float sum = hv.x * wv.x + hv.y * wv.y + hv.z * wv.z + hv.w * wv.w;
#pragma unroll
    for (int o = 32; o > 0; o >>= 1) sum += __shfl_xor(sum, o);
    if (ln == 0) out[b] = sum + pb[0];
}

// ---------------------------------------------------------------------------
extern "C" void kernel_launch(void* const* d_in, const int* in_sizes, int n_in,
                              void* d_out, int out_size, void* d_ws, size_t ws_size,
                              hipStream_t stream) {
    (void)in_sizes; (void)n_in; (void)out_size; (void)ws_size;
    const float* xyz = (const float*)d_in[0];
    const float* pts = (const float*)d_in[1];
    const float* sa1_w1 = (const float*)d_in[2];
    const float* bn1g = (const float*)d_in[3];
    const float* bn1b = (const float*)d_in[4];
    const float* bn1m = (const float*)d_in[5];
    const float* bn1v = (const float*)d_in[6];
    const float* sa1_w2 = (const float*)d_in[7];
    const float* bn2g = (const float*)d_in[8];
    const float* bn2b = (const float*)d_in[9];
    const float* bn2m = (const float*)d_in[10];
    const float* bn2v = (const float*)d_in[11];
    const float* sa1_w3 = (const float*)d_in[12];
    const float* bn3g = (const float*)d_in[13];
    const float* bn3b = (const float*)d_in[14];
    const float* bn3m = (const float*)d_in[15];
    const float* bn3v = (const float*)d_in[16];
    const float* att1w = (const float*)d_in[17];
    const float* att1b = (const float*)d_in[18];
    const float* sa3_w1 = (const float*)d_in[19];
    const float* s1g = (const float*)d_in[20];
    const float* s1b = (const float*)d_in[21];
    const float* s1m = (const float*)d_in[22];
    const float* s1v = (const float*)d_in[23];
    const float* sa3_w2 = (const float*)d_in[24];
    const float* s2g = (const float*)d_in[25];
    const float* s2b = (const float*)d_in[26];
    const float* s2m = (const float*)d_in[27];
    const float* s2v = (const float*)d_in[28];
    const float* sa3_w3 = (const float*)d_in[29];
    const float* s3g = (const float*)d_in[30];
    const float* s3b = (const float*)d_in[31];
    const float* s3m = (const float*)d_in[32];
    const float* s3v = (const float*)d_in[33];
    const float* att3w = (const float*)d_in[34];
    const float* fc1w = (const float*)d_in[35];
    const float* h1g = (const float*)d_in[36];
    const float* h1b = (const float*)d_in[37];
    const float* h1m = (const float*)d_in[38];
    const float* h1v = (const float*)d_in[39];
    const float* fc2w = (const float*)d_in[40];
    const float* h2g = (const float*)d_in[41];
    const float* h2b = (const float*)d_in[42];
    const float* h2m = (const float*)d_in[43];
    const float* h2v = (const float*)d_in[44];
    const float* predw = (const float*)d_in[45];
    const float* predb = (const float*)d_in[46];
    float* out = (float*)d_out;

    // ---- workspace: small linear region, then overlaid big region ----
    char* wsb = (char*)d_ws;
    size_t off = 0;
    auto alloc = [&](size_t bytes) -> void* {
        off = (off + 255) & ~(size_t)255;
        void* p = wsb + off;
        off += bytes;
        return p;
    };
    ushort* Wt2 = (ushort*)alloc(128 * 64 * 2);
    ushort* Wt3 = (ushort*)alloc(256 * 128 * 2);
    ushort* WtS1 = (ushort*)alloc(256 * 288 * 2);
    ushort* WtS2 = (ushort*)alloc(512 * 256 * 2);
    ushort* WtS3 = (ushort*)alloc(1024 * 512 * 2);
    float* sc2 = (float*)alloc(128 * 4);  float* sh2 = (float*)alloc(128 * 4);
    float* sc3 = (float*)alloc(256 * 4);  float* sh3 = (float*)alloc(256 * 4);
    float* scS1 = (float*)alloc(256 * 4); float* shS1 = (float*)alloc(256 * 4);
    float* scS2 = (float*)alloc(512 * 4); float* shS2 = (float*)alloc(512 * 4);
    float* scS3 = (float*)alloc(1024 * 4); float* shS3 = (float*)alloc(1024 * 4);
    float* logits = (float*)alloc((size_t)M_ROWS * 4);
    float* alpha = (float*)alloc((size_t)M_ROWS * 4);
    float* pooled = (float*)alloc(16 * 1024 * 4);
    float* h1buf = (float*)alloc(16 * 512 * 4);
    float* h2buf = (float*)alloc(16 * 256 * 4);

    // big region, overlaid by live range.
    // bigA holds (in time order): {f1,f2,f3,G,g1} then g3 (g3 overwrites all).
    // bigB holds g2 (live S2->S3, overlaps g3's lifetime).
    off = (off + MB - 1) & ~(MB - 1);
    char* bigA = wsb + off;            // 128 MB
    char* bigB = bigA + 128 * MB;      // 64 MB; total ws use = off + 192MB (~195MB)
    ushort* f1 = (ushort*)(bigA);             //  8 MB  [L1, G2)
    ushort* f2 = (ushort*)(bigA + 8 * MB);    // 16 MB  [G2, G3)
    ushort* f3 = (ushort*)(bigA + 24 * MB);   // 32 MB  [G3, gate)
    ushort* G  = (ushort*)(bigA + 56 * MB);   // 36 MB  [gate, S1)
    ushort* g1 = (ushort*)(bigA + 92 * MB);   // 32 MB  [S1, S2)
    ushort* g3 = (ushort*)(bigA);             // 128 MB [S3, pool) — overlays all above
    ushort* g2 = (ushort*)(bigB);             // 64 MB  [S2, S3)

    // ---- prep ----
    PrepArgs pa;
    const float* wsrcs[5] = {sa1_w2, sa1_w3, sa3_w1, sa3_w2, sa3_w3};
    ushort* wdsts[5] = {Wt2, Wt3, WtS1, WtS2, WtS3};
    int wKs[5] = {64, 128, 259, 256, 512};
    int wNs[5] = {128, 256, 256, 512, 1024};
    int wKps[5] = {64, 128, 288, 256, 512};
    const float* gs[5] = {bn2g, bn3g, s1g, s2g, s3g};
    const float* bbs[5] = {bn2b, bn3b, s1b, s2b, s3b};
    const float* mms[5] = {bn2m, bn3m, s1m, s2m, s3m};
    const float* vvs[5] = {bn2v, bn3v, s1v, s2v, s3v};
    float* scs[5] = {sc2, sc3, scS1, scS2, scS3};
    float* shs[5] = {sh2, sh3, shS1, shS2, shS3};
    int Cs[5] = {128, 256, 256, 512, 1024};
    int totalW = 0, totalC = 0;
    for (int i = 0; i < 5; ++i) {
        pa.wsrc[i] = wsrcs[i]; pa.wdst[i] = wdsts[i];
        pa.wK[i] = wKs[i]; pa.wN[i] = wNs[i]; pa.wKp[i] = wKps[i];
        pa.wcount[i] = wNs[i] * wKps[i];
        totalW += pa.wcount[i];
        pa.g[i] = gs[i]; pa.bb[i] = bbs[i]; pa.mm[i] = mms[i]; pa.vv[i] = vvs[i];
        pa.sc[i] = scs[i]; pa.sh[i] = shs[i]; pa.C[i] = Cs[i];
        totalC += Cs[i];
    }
    int prepBlocks = (totalW + totalC + 255) / 256;
    prep_kernel<<<prepBlocks, 256, 0, stream>>>(pa, totalW, totalC);
    zero_kernel<<<(16 * 1024 + 255) / 256, 256, 0, stream>>>(pooled, 16 * 1024);

    // ---- layer 1 ----
    l1_kernel<<<M_ROWS / 4, 256, 0, stream>>>(xyz, pts, sa1_w1, bn1g, bn1b, bn1m, bn1v, f1);
    // ---- layers 2,3 ----
    gemm_bn_relu<<<dim3(M_ROWS / 128, 1), 256, 0, stream>>>(f1, Wt2, sc2, sh2, f2, 128, 64);
    gemm_bn_relu<<<dim3(M_ROWS / 128, 2), 256, 0, stream>>>(f2, Wt3, sc3, sh3, f3, 256, 128);
    // ---- gate + concat ----
    gate_kernel<<<M_ROWS / 4, 256, 0, stream>>>(f3, att1w, att1b, xyz, G);
    // ---- SA3 ----
    gemm_bn_relu<<<dim3(M_ROWS / 128, 2), 256, 0, stream>>>(G, WtS1, scS1, shS1, g1, 256, 288);
    gemm_bn_relu<<<dim3(M_ROWS / 128, 4), 256, 0, stream>>>(g1, WtS2, scS2, shS2, g2, 512, 256);
    gemm_bn_relu<<<dim3(M_ROWS / 128, 8), 256, 0, stream>>>(g2, WtS3, scS3, shS3, g3, 1024, 512);
    // ---- attention pooling ----
    logits_kernel<<<M_ROWS / 4, 256, 0, stream>>>(g3, att3w, logits);
    softmax_kernel<<<16, 1024, 0, stream>>>(logits, alpha);
    pool_kernel<<<dim3(4, 16, 8), 256, 0, stream>>>(g3, alpha, pooled);
    // ---- head ----
    head1_kernel<<<32, 256, 0, stream>>>(pooled, fc1w, h1g, h1b, h1m, h1v, h1buf);
    head2_kernel<<<16, 256, 0, stream>>>(h1buf, fc2w, h2g, h2b, h2m, h2v, h2buf);
    head3_kernel<<<16, 64, 0, stream>>>(h2buf, predw, predb, out);
}

// Round 3
// 491.023 us; speedup vs baseline: 1.0465x; 1.0465x over previous
//
#include <hip/hip_runtime.h>

// ---------------------------------------------------------------------------
// PointNet2-AT inference pipeline, bf16 MFMA GEMMs + fp32 epilogues.
// B=16, N=4096 -> M = 65536 rows everywhere.
// R1: live-range-overlaid workspace (~195MB peak).
// R2: m97-style GEMM (global_load_lds width=16, unpadded LDS), N-fast grid
//     for A-tile L2/LLC reuse, logits fused into S3 epilogue, pool ushort4.
// ---------------------------------------------------------------------------

#define M_ROWS 65536
#define MB ((size_t)1 << 20)

typedef __bf16 bf16x8 __attribute__((ext_vector_type(8)));
typedef float floatx4 __attribute__((ext_vector_type(4)));

__device__ __forceinline__ float b2f(ushort u) {
    unsigned int x = ((unsigned int)u) << 16;
    float f;
    __builtin_memcpy(&f, &x, 4);
    return f;
}
__device__ __forceinline__ ushort f2bf(float f) {
    unsigned int x;
    __builtin_memcpy(&x, &f, 4);
    unsigned int r = x + 0x7fffu + ((x >> 16) & 1u);  // RNE
    return (ushort)(r >> 16);
}
__device__ __forceinline__ float lo16(unsigned u) { return b2f((ushort)(u & 0xffffu)); }
__device__ __forceinline__ float hi16(unsigned u) { return b2f((ushort)(u >> 16)); }

// async global->LDS, 16B per lane; LDS dest = wave-uniform base + lane*16
__device__ __forceinline__ void gl_lds16(const ushort* g, ushort* l) {
    __builtin_amdgcn_global_load_lds(
        (const __attribute__((address_space(1))) unsigned int*)g,
        (__attribute__((address_space(3))) unsigned int*)l, 16, 0, 0);
}

// ---------------------------------------------------------------------------
// Prep: transpose+convert weights fp32[K,N] -> bf16 Wt[N,Kp] (zero-padded K),
// and fold BN params into scale/shift arrays.
// ---------------------------------------------------------------------------
struct PrepArgs {
    const float* wsrc[5]; ushort* wdst[5]; int wK[5], wN[5], wKp[5], wcount[5];
    const float* g[5]; const float* bb[5]; const float* mm[5]; const float* vv[5];
    float* sc[5]; float* sh[5]; int C[5];
};

__global__ __launch_bounds__(256) void prep_kernel(PrepArgs p, int totalW, int totalC) {
    int idx = blockIdx.x * 256 + threadIdx.x;
    if (idx < totalW) {
        int s = 0, base = 0;
        for (s = 0; s < 5; ++s) {
            if (idx < base + p.wcount[s]) break;
            base += p.wcount[s];
        }
        int local = idx - base;
        int n = local / p.wKp[s];
        int k = local - n * p.wKp[s];
        p.wdst[s][local] = (k < p.wK[s]) ? f2bf(p.wsrc[s][k * p.wN[s] + n]) : (ushort)0;
    } else {
        int cidx = idx - totalW;
        if (cidx < totalC) {
            int s = 0, base = 0;
            for (s = 0; s < 5; ++s) {
                if (cidx < base + p.C[s]) break;
                base += p.C[s];
            }
            int c = cidx - base;
            float scv = p.g[s][c] * rsqrtf(p.vv[s][c] + 1e-5f);
            p.sc[s][c] = scv;
            p.sh[s][c] = p.bb[s][c] - p.mm[s][c] * scv;
        }
    }
}

__global__ __launch_bounds__(256) void zero_kernel(float* __restrict__ p, int n) {
    int i = blockIdx.x * 256 + threadIdx.x;
    if (i < n) p[i] = 0.0f;
}

// ---------------------------------------------------------------------------
// Layer 1: [M,6] @ [6,64] + BN + ReLU -> bf16 [M,64].  (K=6: vector kernel)
// ---------------------------------------------------------------------------
__global__ __launch_bounds__(256) void l1_kernel(
    const float* __restrict__ xyz, const float* __restrict__ pts,
    const float* __restrict__ w1, const float* __restrict__ g,
    const float* __restrict__ b, const float* __restrict__ m,
    const float* __restrict__ v, ushort* __restrict__ f1) {
    __shared__ float w[384];
    __shared__ float sc[64], sh[64];
    int tid = threadIdx.x;
    if (tid < 64) {
        float s = g[tid] * rsqrtf(v[tid] + 1e-5f);
        sc[tid] = s;
        sh[tid] = b[tid] - m[tid] * s;
    }
    for (int i = tid; i < 384; i += 256) w[i] = w1[i];
    __syncthreads();
    int r = blockIdx.x * 4 + (tid >> 6);
    int c = tid & 63;
    float x0 = xyz[r * 3], x1 = xyz[r * 3 + 1], x2 = xyz[r * 3 + 2];
    float p0 = pts[r * 3], p1 = pts[r * 3 + 1], p2 = pts[r * 3 + 2];
    float a = x0 * w[c] + x1 * w[64 + c] + x2 * w[128 + c] +
              p0 * w[192 + c] + p1 * w[256 + c] + p2 * w[320 + c];
    a = fmaxf(a * sc[c] + sh[c], 0.0f);
    f1[(size_t)r * 64 + c] = f2bf(a);
}

// ---------------------------------------------------------------------------
// GEMM: C[M,N] = ReLU(BN(A[M,K] @ W[K,N])), A bf16 [M,K], Wt bf16 [N,K].
// grid = (N/128, M/128)  — N-FAST so concurrent blocks share the A M-tile.
// 128x128 tile, BK=32, 4 waves x (4x4) 16x16x32 MFMA. global_load_lds(16B)
// staging into UNPADDED LDS [128][32] (lane-contiguous dest required).
// Optional fused attention-logits epilogue (S3): per-row partial dot with
// attw, 16-lane reduce, atomicAdd into logits[row].
// ---------------------------------------------------------------------------
__global__ __launch_bounds__(256) void gemm_bn_relu(
    const ushort* __restrict__ A, const ushort* __restrict__ Wt,
    const float* __restrict__ scale, const float* __restrict__ shift,
    ushort* __restrict__ C, int N, int K,
    const float* __restrict__ attw, float* __restrict__ logits) {
    __shared__ ushort As[128 * 32];
    __shared__ ushort Bs[128 * 32];
    const int tid = threadIdx.x;
    const int bn0 = blockIdx.x * 128;
    const int bm0 = blockIdx.y * 128;
    const int wid = tid >> 6, ln = tid & 63;
    const int wr = wid >> 1, wc = wid & 1;
    const int lm = ln & 15, q = ln >> 4;

    floatx4 acc[4][4];
#pragma unroll
    for (int i = 0; i < 4; ++i)
#pragma unroll
        for (int j = 0; j < 4; ++j) acc[i][j] = (floatx4){0.f, 0.f, 0.f, 0.f};

    const int srow = tid >> 2;            // 0..63
    const int skc = (tid & 3) << 3;       // 0,8,16,24
    const int sldst = wid * 512;          // wave-uniform LDS base (ushort idx)

    for (int kt = 0; kt < K; kt += 32) {
#pragma unroll
        for (int l = 0; l < 2; ++l) {
            gl_lds16(&A[(size_t)(bm0 + l * 64 + srow) * K + kt + skc],
                     &As[l * 2048 + sldst]);
            gl_lds16(&Wt[(size_t)(bn0 + l * 64 + srow) * K + kt + skc],
                     &Bs[l * 2048 + sldst]);
        }
        asm volatile("s_waitcnt vmcnt(0)" ::: "memory");
        __syncthreads();
        bf16x8 af[4], bf[4];
#pragma unroll
        for (int i = 0; i < 4; ++i)
            af[i] = *(const bf16x8*)(&As[(wr * 64 + i * 16 + lm) * 32 + q * 8]);
#pragma unroll
        for (int i = 0; i < 4; ++i)
            bf[i] = *(const bf16x8*)(&Bs[(wc * 64 + i * 16 + lm) * 32 + q * 8]);
#pragma unroll
        for (int mi = 0; mi < 4; ++mi)
#pragma unroll
            for (int ni = 0; ni < 4; ++ni)
                acc[mi][ni] = __builtin_amdgcn_mfma_f32_16x16x32_bf16(
                    af[mi], bf[ni], acc[mi][ni], 0, 0, 0);
        __syncthreads();
    }

    float s[4], t[4], aw[4];
#pragma unroll
    for (int ni = 0; ni < 4; ++ni) {
        int gcol = bn0 + wc * 64 + ni * 16 + lm;
        s[ni] = scale[gcol];
        t[ni] = shift[gcol];
        aw[ni] = attw ? attw[gcol] : 0.0f;
    }
#pragma unroll
    for (int mi = 0; mi < 4; ++mi) {
        int grow0 = bm0 + wr * 64 + mi * 16 + q * 4;
#pragma unroll
        for (int r = 0; r < 4; ++r) {
            float p = 0.0f;
#pragma unroll
            for (int ni = 0; ni < 4; ++ni) {
                int gcol = bn0 + wc * 64 + ni * 16 + lm;
                float val = fmaxf(acc[mi][ni][r] * s[ni] + t[ni], 0.0f);
                C[(size_t)(grow0 + r) * N + gcol] = f2bf(val);
                p += val * aw[ni];
            }
            if (logits) {
#pragma unroll
                for (int o = 8; o > 0; o >>= 1) p += __shfl_xor(p, o, 16);
                if (lm == 0) atomicAdd(&logits[grow0 + r], p);
            }
        }
    }
}

// ---------------------------------------------------------------------------
// Gate: s = sigmoid(f3 . att_w + att_b); G = [bf16(xyz), f3*s, zeros] [M,288]
// ---------------------------------------------------------------------------
__global__ __launch_bounds__(256) void gate_kernel(
    const ushort* __restrict__ f3, const float* __restrict__ attw,
    const float* __restrict__ attb, const float* __restrict__ xyz,
    ushort* __restrict__ G) {
    int tid = threadIdx.x;
    int ln = tid & 63, wid = tid >> 6;
    int r = blockIdx.x * 4 + wid;
    ushort4 fv = *(const ushort4*)&f3[(size_t)r * 256 + ln * 4];
    float f0 = b2f(fv.x), f1 = b2f(fv.y), f2 = b2f(fv.z), f3v = b2f(fv.w);
    float4 aw = *(const float4*)&attw[ln * 4];
    float sum = f0 * aw.x + f1 * aw.y + f2 * aw.z + f3v * aw.w;
#pragma unroll
    for (int o = 32; o > 0; o >>= 1) sum += __shfl_xor(sum, o);
    float s = 1.0f / (1.0f + expf(-(sum + attb[0])));
    size_t gb = (size_t)r * 288;
    G[gb + 3 + ln * 4 + 0] = f2bf(f0 * s);
    G[gb + 3 + ln * 4 + 1] = f2bf(f1 * s);
    G[gb + 3 + ln * 4 + 2] = f2bf(f2 * s);
    G[gb + 3 + ln * 4 + 3] = f2bf(f3v * s);
    if (ln < 3) G[gb + ln] = f2bf(xyz[r * 3 + ln]);
    if (ln >= 3 && ln < 32) G[gb + 256 + ln] = 0;  // cols 259..287 zero pad
}

// ---------------------------------------------------------------------------
// Softmax over N=4096 per batch; one block of 1024 per batch.
// ---------------------------------------------------------------------------
__global__ __launch_bounds__(1024) void softmax_kernel(
    const float* __restrict__ logits, float* __restrict__ alpha) {
    __shared__ float red[1024];
    int b = blockIdx.x, t = threadIdx.x;
    float4 v = *(const float4*)&logits[b * 4096 + t * 4];
    float mx = fmaxf(fmaxf(v.x, v.y), fmaxf(v.z, v.w));
    red[t] = mx;
    __syncthreads();
    for (int s = 512; s > 0; s >>= 1) {
        if (t < s) red[t] = fmaxf(red[t], red[t + s]);
        __syncthreads();
    }
    float M = red[0];
    __syncthreads();
    float e0 = expf(v.x - M), e1 = expf(v.y - M), e2 = expf(v.z - M), e3 = expf(v.w - M);
    red[t] = e0 + e1 + e2 + e3;
    __syncthreads();
    for (int s = 512; s > 0; s >>= 1) {
        if (t < s) red[t] += red[t + s];
        __syncthreads();
    }
    float inv = 1.0f / red[0];
    *(float4*)&alpha[b * 4096 + t * 4] = make_float4(e0 * inv, e1 * inv, e2 * inv, e3 * inv);
}

// ---------------------------------------------------------------------------
// Pool: pooled[b,c] = sum_n alpha[b,n]*g3[b,n,c]; each thread: 4 cols (ushort4)
// grid (1, 16 b, 16 nsplit) x 256
// ---------------------------------------------------------------------------
__global__ __launch_bounds__(256) void pool_kernel(
    const ushort* __restrict__ g3, const float* __restrict__ alpha,
    float* __restrict__ pooled) {
    int c4 = threadIdx.x * 4;
    int b = blockIdx.y;
    int n0 = blockIdx.z * 256;
    const ushort* base = g3 + ((size_t)b * 4096 + n0) * 1024 + c4;
    const float* al = alpha + b * 4096 + n0;
    float a0 = 0.f, a1 = 0.f, a2 = 0.f, a3 = 0.f;
#pragma unroll 4
    for (int n = 0; n < 256; ++n) {
        float w = al[n];
        ushort4 gv = *(const ushort4*)&base[(size_t)n * 1024];
        a0 += w * b2f(gv.x); a1 += w * b2f(gv.y);
        a2 += w * b2f(gv.z); a3 += w * b2f(gv.w);
    }
    float* pd = &pooled[b * 1024 + c4];
    atomicAdd(pd + 0, a0); atomicAdd(pd + 1, a1);
    atomicAdd(pd + 2, a2); atomicAdd(pd + 3, a3);
}

// ---------------------------------------------------------------------------
// Head
// ---------------------------------------------------------------------------
__global__ __launch_bounds__(256) void head1_kernel(
    const float* __restrict__ pooled, const float* __restrict__ w,
    const float* __restrict__ g, const float* __restrict__ bb,
    const float* __restrict__ m, const float* __restrict__ v,
    float* __restrict__ h1) {
    int idx = blockIdx.x * 256 + threadIdx.x;  // 16*512
    int b = idx >> 9, c = idx & 511;
    float sc = g[c] * rsqrtf(v[c] + 1e-5f);
    float sh = bb[c] - m[c] * sc;
    const float* pr = pooled + b * 1024;
    float acc = 0.0f;
    for (int k = 0; k < 1024; ++k) acc += pr[k] * w[k * 512 + c];
    h1[idx] = fmaxf(acc * sc + sh, 0.0f);
}

__global__ __launch_bounds__(256) void head2_kernel(
    const float* __restrict__ h1, const float* __restrict__ w,
    const float* __restrict__ g, const float* __restrict__ bb,
    const float* __restrict__ m, const float* __restrict__ v,
    float* __restrict__ h2) {
    int b = blockIdx.x, c = threadIdx.x;  // 16 x 256
    float sc = g[c] * rsqrtf(v[c] + 1e-5f);
    float sh = bb[c] - m[c] * sc;
    const float* hr = h1 + b * 512;
    float acc = 0.0f;
    for (int k = 0; k < 512; ++k) acc += hr[k] * w[k * 256 + c];
    h2[b * 256 + c] = fmaxf(acc * sc + sh, 0.0f);
}

__global__ __launch_bounds__(64) void head3_kernel(
    const float* __restrict__ h2, const float* __restrict__ pw,
    const float* __restrict__ pb, float* __restrict__ out) {
    int b = blockIdx.x, ln = threadIdx.x;
    float4 hv = *(const float4*)&h2[b * 256 + ln * 4];
    float4 wv = *(const float4*)&pw[ln * 4];
    float sum = hv.x * wv.x + hv.y * wv.y + hv.z * wv.z + hv.w * wv.w;
#pragma unroll
    for (int o = 32; o > 0; o >>= 1) sum += __shfl_xor(sum, o);
    if (ln == 0) out[b] = sum + pb[0];
}

// ---------------------------------------------------------------------------
extern "C" void kernel_launch(void* const* d_in, const int* in_sizes, int n_in,
                              void* d_out, int out_size, void* d_ws, size_t ws_size,
                              hipStream_t stream) {
    (void)in_sizes; (void)n_in; (void)out_size; (void)ws_size;
    const float* xyz = (const float*)d_in[0];
    const float* pts = (const float*)d_in[1];
    const float* sa1_w1 = (const float*)d_in[2];
    const float* bn1g = (const float*)d_in[3];
    const float* bn1b = (const float*)d_in[4];
    const float* bn1m = (const float*)d_in[5];
    const float* bn1v = (const float*)d_in[6];
    const float* sa1_w2 = (const float*)d_in[7];
    const float* bn2g = (const float*)d_in[8];
    const float* bn2b = (const float*)d_in[9];
    const float* bn2m = (const float*)d_in[10];
    const float* bn2v = (const float*)d_in[11];
    const float* sa1_w3 = (const float*)d_in[12];
    const float* bn3g = (const float*)d_in[13];
    const float* bn3b = (const float*)d_in[14];
    const float* bn3m = (const float*)d_in[15];
    const float* bn3v = (const float*)d_in[16];
    const float* att1w = (const float*)d_in[17];
    const float* att1b = (const float*)d_in[18];
    const float* sa3_w1 = (const float*)d_in[19];
    const float* s1g = (const float*)d_in[20];
    const float* s1b = (const float*)d_in[21];
    const float* s1m = (const float*)d_in[22];
    const float* s1v = (const float*)d_in[23];
    const float* sa3_w2 = (const float*)d_in[24];
    const float* s2g = (const float*)d_in[25];
    const float* s2b = (const float*)d_in[26];
    const float* s2m = (const float*)d_in[27];
    const float* s2v = (const float*)d_in[28];
    const float* sa3_w3 = (const float*)d_in[29];
    const float* s3g = (const float*)d_in[30];
    const float* s3b = (const float*)d_in[31];
    const float* s3m = (const float*)d_in[32];
    const float* s3v = (const float*)d_in[33];
    const float* att3w = (const float*)d_in[34];
    const float* fc1w = (const float*)d_in[35];
    const float* h1g = (const float*)d_in[36];
    const float* h1b = (const float*)d_in[37];
    const float* h1m = (const float*)d_in[38];
    const float* h1v = (const float*)d_in[39];
    const float* fc2w = (const float*)d_in[40];
    const float* h2g = (const float*)d_in[41];
    const float* h2b = (const float*)d_in[42];
    const float* h2m = (const float*)d_in[43];
    const float* h2v = (const float*)d_in[44];
    const float* predw = (const float*)d_in[45];
    const float* predb = (const float*)d_in[46];
    float* out = (float*)d_out;

    // ---- workspace: small linear region, then overlaid big region ----
    char* wsb = (char*)d_ws;
    size_t off = 0;
    auto alloc = [&](size_t bytes) -> void* {
        off = (off + 255) & ~(size_t)255;
        void* p = wsb + off;
        off += bytes;
        return p;
    };
    ushort* Wt2 = (ushort*)alloc(128 * 64 * 2);
    ushort* Wt3 = (ushort*)alloc(256 * 128 * 2);
    ushort* WtS1 = (ushort*)alloc(256 * 288 * 2);
    ushort* WtS2 = (ushort*)alloc(512 * 256 * 2);
    ushort* WtS3 = (ushort*)alloc(1024 * 512 * 2);
    float* sc2 = (float*)alloc(128 * 4);  float* sh2 = (float*)alloc(128 * 4);
    float* sc3 = (float*)alloc(256 * 4);  float* sh3 = (float*)alloc(256 * 4);
    float* scS1 = (float*)alloc(256 * 4); float* shS1 = (float*)alloc(256 * 4);
    float* scS2 = (float*)alloc(512 * 4); float* shS2 = (float*)alloc(512 * 4);
    float* scS3 = (float*)alloc(1024 * 4); float* shS3 = (float*)alloc(1024 * 4);
    float* logits = (float*)alloc((size_t)M_ROWS * 4);
    float* alpha = (float*)alloc((size_t)M_ROWS * 4);
    float* pooled = (float*)alloc(16 * 1024 * 4);
    float* h1buf = (float*)alloc(16 * 512 * 4);
    float* h2buf = (float*)alloc(16 * 256 * 4);

    // big region, overlaid by live range.
    off = (off + MB - 1) & ~(MB - 1);
    char* bigA = wsb + off;            // 128 MB
    char* bigB = bigA + 128 * MB;      // 64 MB
    ushort* f1 = (ushort*)(bigA);             //  8 MB  [L1, G2)
    ushort* f2 = (ushort*)(bigA + 8 * MB);    // 16 MB  [G2, G3)
    ushort* f3 = (ushort*)(bigA + 24 * MB);   // 32 MB  [G3, gate)
    ushort* G  = (ushort*)(bigA + 56 * MB);   // 36 MB  [gate, S1)
    ushort* g1 = (ushort*)(bigA + 92 * MB);   // 32 MB  [S1, S2)
    ushort* g3 = (ushort*)(bigA);             // 128 MB [S3, pool)
    ushort* g2 = (ushort*)(bigB);             // 64 MB  [S2, S3)

    // ---- prep ----
    PrepArgs pa;
    const float* wsrcs[5] = {sa1_w2, sa1_w3, sa3_w1, sa3_w2, sa3_w3};
    ushort* wdsts[5] = {Wt2, Wt3, WtS1, WtS2, WtS3};
    int wKs[5] = {64, 128, 259, 256, 512};
    int wNs[5] = {128, 256, 256, 512, 1024};
    int wKps[5] = {64, 128, 288, 256, 512};
    const float* gs[5] = {bn2g, bn3g, s1g, s2g, s3g};
    const float* bbs[5] = {bn2b, bn3b, s1b, s2b, s3b};
    const float* mms[5] = {bn2m, bn3m, s1m, s2m, s3m};
    const float* vvs[5] = {bn2v, bn3v, s1v, s2v, s3v};
    float* scs[5] = {sc2, sc3, scS1, scS2, scS3};
    float* shs[5] = {sh2, sh3, shS1, shS2, shS3};
    int Cs[5] = {128, 256, 256, 512, 1024};
    int totalW = 0, totalC = 0;
    for (int i = 0; i < 5; ++i) {
        pa.wsrc[i] = wsrcs[i]; pa.wdst[i] = wdsts[i];
        pa.wK[i] = wKs[i]; pa.wN[i] = wNs[i]; pa.wKp[i] = wKps[i];
        pa.wcount[i] = wNs[i] * wKps[i];
        totalW += pa.wcount[i];
        pa.g[i] = gs[i]; pa.bb[i] = bbs[i]; pa.mm[i] = mms[i]; pa.vv[i] = vvs[i];
        pa.sc[i] = scs[i]; pa.sh[i] = shs[i]; pa.C[i] = Cs[i];
        totalC += Cs[i];
    }
    int prepBlocks = (totalW + totalC + 255) / 256;
    prep_kernel<<<prepBlocks, 256, 0, stream>>>(pa, totalW, totalC);
    zero_kernel<<<(16 * 1024 + 255) / 256, 256, 0, stream>>>(pooled, 16 * 1024);
    zero_kernel<<<(M_ROWS + 255) / 256, 256, 0, stream>>>(logits, M_ROWS);

    // ---- layer 1 ----
    l1_kernel<<<M_ROWS / 4, 256, 0, stream>>>(xyz, pts, sa1_w1, bn1g, bn1b, bn1m, bn1v, f1);
    // ---- layers 2,3 (grid: N-tiles fast, M-tiles slow) ----
    gemm_bn_relu<<<dim3(1, M_ROWS / 128), 256, 0, stream>>>(f1, Wt2, sc2, sh2, f2, 128, 64, nullptr, nullptr);
    gemm_bn_relu<<<dim3(2, M_ROWS / 128), 256, 0, stream>>>(f2, Wt3, sc3, sh3, f3, 256, 128, nullptr, nullptr);
    // ---- gate + concat ----
    gate_kernel<<<M_ROWS / 4, 256, 0, stream>>>(f3, att1w, att1b, xyz, G);
    // ---- SA3 ----
    gemm_bn_relu<<<dim3(2, M_ROWS / 128), 256, 0, stream>>>(G, WtS1, scS1, shS1, g1, 256, 288, nullptr, nullptr);
    gemm_bn_relu<<<dim3(4, M_ROWS / 128), 256, 0, stream>>>(g1, WtS2, scS2, shS2, g2, 512, 256, nullptr, nullptr);
    // S3: fused attention-logits epilogue
    gemm_bn_relu<<<dim3(8, M_ROWS / 128), 256, 0, stream>>>(g2, WtS3, scS3, shS3, g3, 1024, 512, att3w, logits);
    // ---- attention pooling ----
    softmax_kernel<<<16, 1024, 0, stream>>>(logits, alpha);
    pool_kernel<<<dim3(1, 16, 16), 256, 0, stream>>>(g3, alpha, pooled);
    // ---- head ----
    head1_kernel<<<32, 256, 0, stream>>>(pooled, fc1w, h1g, h1b, h1m, h1v, h1buf);
    head2_kernel<<<16, 256, 0, stream>>>(h1buf, fc2w, h2g, h2b, h2m, h2v, h2buf);
    head3_kernel<<<16, 64, 0, stream>>>(h2buf, predw, predb, out);
}

// Round 4
// 468.208 us; speedup vs baseline: 1.0975x; 1.0487x over previous
//
#include <hip/hip_runtime.h>

// ---------------------------------------------------------------------------
// PointNet2-AT inference pipeline, bf16 MFMA GEMMs + fp32 epilogues.
// B=16, N=4096 -> M = 65536 rows everywhere.
// R1: live-range-overlaid workspace (~195MB peak).
// R2: m97-style GEMM (global_load_lds width=16, unpadded LDS).
// R3 post-mortem: S3 fabric-BW-bound at ~2.9TB/s; N-fast grid spread
//     same-A blocks across XCDs (A fetched ~4x); logits atomics +16MB RMW.
// R4: XCD-aware swizzle (all numN N-blocks of an M-tile -> same XCD, adjacent
//     slots); logits via per-(N-tile, wave-col) partial slices (no atomics).
// ---------------------------------------------------------------------------

#define M_ROWS 65536
#define MB ((size_t)1 << 20)

typedef __bf16 bf16x8 __attribute__((ext_vector_type(8)));
typedef float floatx4 __attribute__((ext_vector_type(4)));

__device__ __forceinline__ float b2f(ushort u) {
    unsigned int x = ((unsigned int)u) << 16;
    float f;
    __builtin_memcpy(&f, &x, 4);
    return f;
}
__device__ __forceinline__ ushort f2bf(float f) {
    unsigned int x;
    __builtin_memcpy(&x, &f, 4);
    unsigned int r = x + 0x7fffu + ((x >> 16) & 1u);  // RNE
    return (ushort)(r >> 16);
}

// async global->LDS, 16B per lane; LDS dest = wave-uniform base + lane*16
__device__ __forceinline__ void gl_lds16(const ushort* g, ushort* l) {
    __builtin_amdgcn_global_load_lds(
        (const __attribute__((address_space(1))) unsigned int*)g,
        (__attribute__((address_space(3))) unsigned int*)l, 16, 0, 0);
}

// ---------------------------------------------------------------------------
// Prep: transpose+convert weights fp32[K,N] -> bf16 Wt[N,Kp] (zero-padded K),
// and fold BN params into scale/shift arrays.
// ---------------------------------------------------------------------------
struct PrepArgs {
    const float* wsrc[5]; ushort* wdst[5]; int wK[5], wN[5], wKp[5], wcount[5];
    const float* g[5]; const float* bb[5]; const float* mm[5]; const float* vv[5];
    float* sc[5]; float* sh[5]; int C[5];
};

__global__ __launch_bounds__(256) void prep_kernel(PrepArgs p, int totalW, int totalC) {
    int idx = blockIdx.x * 256 + threadIdx.x;
    if (idx < totalW) {
        int s = 0, base = 0;
        for (s = 0; s < 5; ++s) {
            if (idx < base + p.wcount[s]) break;
            base += p.wcount[s];
        }
        int local = idx - base;
        int n = local / p.wKp[s];
        int k = local - n * p.wKp[s];
        p.wdst[s][local] = (k < p.wK[s]) ? f2bf(p.wsrc[s][k * p.wN[s] + n]) : (ushort)0;
    } else {
        int cidx = idx - totalW;
        if (cidx < totalC) {
            int s = 0, base = 0;
            for (s = 0; s < 5; ++s) {
                if (cidx < base + p.C[s]) break;
                base += p.C[s];
            }
            int c = cidx - base;
            float scv = p.g[s][c] * rsqrtf(p.vv[s][c] + 1e-5f);
            p.sc[s][c] = scv;
            p.sh[s][c] = p.bb[s][c] - p.mm[s][c] * scv;
        }
    }
}

__global__ __launch_bounds__(256) void zero_kernel(float* __restrict__ p, int n) {
    int i = blockIdx.x * 256 + threadIdx.x;
    if (i < n) p[i] = 0.0f;
}

// ---------------------------------------------------------------------------
// Layer 1: [M,6] @ [6,64] + BN + ReLU -> bf16 [M,64].  (K=6: vector kernel)
// ---------------------------------------------------------------------------
__global__ __launch_bounds__(256) void l1_kernel(
    const float* __restrict__ xyz, const float* __restrict__ pts,
    const float* __restrict__ w1, const float* __restrict__ g,
    const float* __restrict__ b, const float* __restrict__ m,
    const float* __restrict__ v, ushort* __restrict__ f1) {
    __shared__ float w[384];
    __shared__ float sc[64], sh[64];
    int tid = threadIdx.x;
    if (tid < 64) {
        float s = g[tid] * rsqrtf(v[tid] + 1e-5f);
        sc[tid] = s;
        sh[tid] = b[tid] - m[tid] * s;
    }
    for (int i = tid; i < 384; i += 256) w[i] = w1[i];
    __syncthreads();
    int r = blockIdx.x * 4 + (tid >> 6);
    int c = tid & 63;
    float x0 = xyz[r * 3], x1 = xyz[r * 3 + 1], x2 = xyz[r * 3 + 2];
    float p0 = pts[r * 3], p1 = pts[r * 3 + 1], p2 = pts[r * 3 + 2];
    float a = x0 * w[c] + x1 * w[64 + c] + x2 * w[128 + c] +
              p0 * w[192 + c] + p1 * w[256 + c] + p2 * w[320 + c];
    a = fmaxf(a * sc[c] + sh[c], 0.0f);
    f1[(size_t)r * 64 + c] = f2bf(a);
}

// ---------------------------------------------------------------------------
// GEMM: C[M,N] = ReLU(BN(A[M,K] @ W[K,N])), A bf16 [M,K], Wt bf16 [N,K].
// Grid: 1D, numM*numN blocks, XCD-swizzled:
//   L = chunk*(8*numN) + n*8 + xcd;  m = chunk*8 + xcd   (numM%8==0)
// -> all numN N-blocks of M-tile m on ONE XCD in adjacent slots => A-tile
//    fetched once per XCD L2. 128x128 tile, BK=32, 4 waves x (4x4) 16x16x32
//    MFMA, global_load_lds(16B) into unpadded LDS [128][32].
// Fused logits (S3): partial dot over this wave-col's 64 cols, 16-lane
// reduce, store to slice logitsP[nt*2+wc][row]. 16 slices, no atomics.
// ---------------------------------------------------------------------------
__global__ __launch_bounds__(256) void gemm_bn_relu(
    const ushort* __restrict__ A, const ushort* __restrict__ Wt,
    const float* __restrict__ scale, const float* __restrict__ shift,
    ushort* __restrict__ C, int N, int K, int numN,
    const float* __restrict__ attw, float* __restrict__ logitsP) {
    __shared__ ushort As[128 * 32];
    __shared__ ushort Bs[128 * 32];
    const int tid = threadIdx.x;
    const int g8 = numN * 8;
    const int chunk = blockIdx.x / g8;
    const int rem = blockIdx.x - chunk * g8;
    const int nt = rem >> 3;
    const int xcd = rem & 7;
    const int bn0 = nt * 128;
    const int bm0 = (chunk * 8 + xcd) * 128;

    const int wid = tid >> 6, ln = tid & 63;
    const int wr = wid >> 1, wc = wid & 1;
    const int lm = ln & 15, q = ln >> 4;

    floatx4 acc[4][4];
#pragma unroll
    for (int i = 0; i < 4; ++i)
#pragma unroll
        for (int j = 0; j < 4; ++j) acc[i][j] = (floatx4){0.f, 0.f, 0.f, 0.f};

    const int srow = tid >> 2;            // 0..63
    const int skc = (tid & 3) << 3;       // 0,8,16,24
    const int sldst = wid * 512;          // wave-uniform LDS base (ushort idx)

    for (int kt = 0; kt < K; kt += 32) {
#pragma unroll
        for (int l = 0; l < 2; ++l) {
            gl_lds16(&A[(size_t)(bm0 + l * 64 + srow) * K + kt + skc],
                     &As[l * 2048 + sldst]);
            gl_lds16(&Wt[(size_t)(bn0 + l * 64 + srow) * K + kt + skc],
                     &Bs[l * 2048 + sldst]);
        }
        asm volatile("s_waitcnt vmcnt(0)" ::: "memory");
        __syncthreads();
        bf16x8 af[4], bf[4];
#pragma unroll
        for (int i = 0; i < 4; ++i)
            af[i] = *(const bf16x8*)(&As[(wr * 64 + i * 16 + lm) * 32 + q * 8]);
#pragma unroll
        for (int i = 0; i < 4; ++i)
            bf[i] = *(const bf16x8*)(&Bs[(wc * 64 + i * 16 + lm) * 32 + q * 8]);
#pragma unroll
        for (int mi = 0; mi < 4; ++mi)
#pragma unroll
            for (int ni = 0; ni < 4; ++ni)
                acc[mi][ni] = __builtin_amdgcn_mfma_f32_16x16x32_bf16(
                    af[mi], bf[ni], acc[mi][ni], 0, 0, 0);
        __syncthreads();
    }

    float s[4], t[4], aw[4];
#pragma unroll
    for (int ni = 0; ni < 4; ++ni) {
        int gcol = bn0 + wc * 64 + ni * 16 + lm;
        s[ni] = scale[gcol];
        t[ni] = shift[gcol];
        aw[ni] = attw ? attw[gcol] : 0.0f;
    }
#pragma unroll
    for (int mi = 0; mi < 4; ++mi) {
        int grow0 = bm0 + wr * 64 + mi * 16 + q * 4;
#pragma unroll
        for (int r = 0; r < 4; ++r) {
            float p = 0.0f;
#pragma unroll
            for (int ni = 0; ni < 4; ++ni) {
                int gcol = bn0 + wc * 64 + ni * 16 + lm;
                float val = fmaxf(acc[mi][ni][r] * s[ni] + t[ni], 0.0f);
                C[(size_t)(grow0 + r) * N + gcol] = f2bf(val);
                p += val * aw[ni];
            }
            if (logitsP) {
#pragma unroll
                for (int o = 8; o > 0; o >>= 1) p += __shfl_xor(p, o, 16);
                if (lm == 0)
                    logitsP[(size_t)(nt * 2 + wc) * M_ROWS + grow0 + r] = p;
            }
        }
    }
}

// ---------------------------------------------------------------------------
// Gate: s = sigmoid(f3 . att_w + att_b); G = [bf16(xyz), f3*s, zeros] [M,288]
// ---------------------------------------------------------------------------
__global__ __launch_bounds__(256) void gate_kernel(
    const ushort* __restrict__ f3, const float* __restrict__ attw,
    const float* __restrict__ attb, const float* __restrict__ xyz,
    ushort* __restrict__ G) {
    int tid = threadIdx.x;
    int ln = tid & 63, wid = tid >> 6;
    int r = blockIdx.x * 4 + wid;
    ushort4 fv = *(const ushort4*)&f3[(size_t)r * 256 + ln * 4];
    float f0 = b2f(fv.x), f1 = b2f(fv.y), f2 = b2f(fv.z), f3v = b2f(fv.w);
    float4 aw = *(const float4*)&attw[ln * 4];
    float sum = f0 * aw.x + f1 * aw.y + f2 * aw.z + f3v * aw.w;
#pragma unroll
    for (int o = 32; o > 0; o >>= 1) sum += __shfl_xor(sum, o);
    float s = 1.0f / (1.0f + expf(-(sum + attb[0])));
    size_t gb = (size_t)r * 288;
    G[gb + 3 + ln * 4 + 0] = f2bf(f0 * s);
    G[gb + 3 + ln * 4 + 1] = f2bf(f1 * s);
    G[gb + 3 + ln * 4 + 2] = f2bf(f2 * s);
    G[gb + 3 + ln * 4 + 3] = f2bf(f3v * s);
    if (ln < 3) G[gb + ln] = f2bf(xyz[r * 3 + ln]);
    if (ln >= 3 && ln < 32) G[gb + 256 + ln] = 0;  // cols 259..287 zero pad
}

// ---------------------------------------------------------------------------
// Softmax over N=4096 per batch (logits = sum of 16 partial slices).
// ---------------------------------------------------------------------------
__global__ __launch_bounds__(1024) void softmax_kernel(
    const float* __restrict__ logitsP, float* __restrict__ alpha) {
    __shared__ float red[1024];
    int b = blockIdx.x, t = threadIdx.x;
    float4 v = (float4){0.f, 0.f, 0.f, 0.f};
#pragma unroll
    for (int j = 0; j < 16; ++j) {
        float4 pv = *(const float4*)&logitsP[(size_t)j * M_ROWS + b * 4096 + t * 4];
        v.x += pv.x; v.y += pv.y; v.z += pv.z; v.w += pv.w;
    }
    float mx = fmaxf(fmaxf(v.x, v.y), fmaxf(v.z, v.w));
    red[t] = mx;
    __syncthreads();
    for (int s = 512; s > 0; s >>= 1) {
        if (t < s) red[t] = fmaxf(red[t], red[t + s]);
        __syncthreads();
    }
    float M = red[0];
    __syncthreads();
    float e0 = expf(v.x - M), e1 = expf(v.y - M), e2 = expf(v.z - M), e3 = expf(v.w - M);
    red[t] = e0 + e1 + e2 + e3;
    __syncthreads();
    for (int s = 512; s > 0; s >>= 1) {
        if (t < s) red[t] += red[t + s];
        __syncthreads();
    }
    float inv = 1.0f / red[0];
    *(float4*)&alpha[b * 4096 + t * 4] = make_float4(e0 * inv, e1 * inv, e2 * inv, e3 * inv);
}

// ---------------------------------------------------------------------------
// Pool: pooled[b,c] = sum_n alpha[b,n]*g3[b,n,c]; each thread: 4 cols (ushort4)
// ---------------------------------------------------------------------------
__global__ __launch_bounds__(256) void pool_kernel(
    const ushort* __restrict__ g3, const float* __restrict__ alpha,
    float* __restrict__ pooled) {
    int c4 = threadIdx.x * 4;
    int b = blockIdx.y;
    int n0 = blockIdx.z * 256;
    const ushort* base = g3 + ((size_t)b * 4096 + n0) * 1024 + c4;
    const float* al = alpha + b * 4096 + n0;
    float a0 = 0.f, a1 = 0.f, a2 = 0.f, a3 = 0.f;
#pragma unroll 4
    for (int n = 0; n < 256; ++n) {
        float w = al[n];
        ushort4 gv = *(const ushort4*)&base[(size_t)n * 1024];
        a0 += w * b2f(gv.x); a1 += w * b2f(gv.y);
        a2 += w * b2f(gv.z); a3 += w * b2f(gv.w);
    }
    float* pd = &pooled[b * 1024 + c4];
    atomicAdd(pd + 0, a0); atomicAdd(pd + 1, a1);
    atomicAdd(pd + 2, a2); atomicAdd(pd + 3, a3);
}

// ---------------------------------------------------------------------------
// Head
// ---------------------------------------------------------------------------
__global__ __launch_bounds__(256) void head1_kernel(
    const float* __restrict__ pooled, const float* __restrict__ w,
    const float* __restrict__ g, const float* __restrict__ bb,
    const float* __restrict__ m, const float* __restrict__ v,
    float* __restrict__ h1) {
    int idx = blockIdx.x * 256 + threadIdx.x;  // 16*512
    int b = idx >> 9, c = idx & 511;
    float sc = g[c] * rsqrtf(v[c] + 1e-5f);
    float sh = bb[c] - m[c] * sc;
    const float* pr = pooled + b * 1024;
    float acc = 0.0f;
    for (int k = 0; k < 1024; ++k) acc += pr[k] * w[k * 512 + c];
    h1[idx] = fmaxf(acc * sc + sh, 0.0f);
}

__global__ __launch_bounds__(256) void head2_kernel(
    const float* __restrict__ h1, const float* __restrict__ w,
    const float* __restrict__ g, const float* __restrict__ bb,
    const float* __restrict__ m, const float* __restrict__ v,
    float* __restrict__ h2) {
    int b = blockIdx.x, c = threadIdx.x;  // 16 x 256
    float sc = g[c] * rsqrtf(v[c] + 1e-5f);
    float sh = bb[c] - m[c] * sc;
    const float* hr = h1 + b * 512;
    float acc = 0.0f;
    for (int k = 0; k < 512; ++k) acc += hr[k] * w[k * 256 + c];
    h2[b * 256 + c] = fmaxf(acc * sc + sh, 0.0f);
}

__global__ __launch_bounds__(64) void head3_kernel(
    const float* __restrict__ h2, const float* __restrict__ pw,
    const float* __restrict__ pb, float* __restrict__ out) {
    int b = blockIdx.x, ln = threadIdx.x;
    float4 hv = *(const float4*)&h2[b * 256 + ln * 4];
    float4 wv = *(const float4*)&pw[ln * 4];
    float sum = hv.x * wv.x + hv.y * wv.y + hv.z * wv.z + hv.w * wv.w;
#pragma unroll
    for (int o = 32; o > 0; o >>= 1) sum += __shfl_xor(sum, o);
    if (ln == 0) out[b] = sum + pb[0];
}

// ---------------------------------------------------------------------------
extern "C" void kernel_launch(void* const* d_in, const int* in_sizes, int n_in,
                              void* d_out, int out_size, void* d_ws, size_t ws_size,
                              hipStream_t stream) {
    (void)in_sizes; (void)n_in; (void)out_size; (void)ws_size;
    const float* xyz = (const float*)d_in[0];
    const float* pts = (const float*)d_in[1];
    const float* sa1_w1 = (const float*)d_in[2];
    const float* bn1g = (const float*)d_in[3];
    const float* bn1b = (const float*)d_in[4];
    const float* bn1m = (const float*)d_in[5];
    const float* bn1v = (const float*)d_in[6];
    const float* sa1_w2 = (const float*)d_in[7];
    const float* bn2g = (const float*)d_in[8];
    const float* bn2b = (const float*)d_in[9];
    const float* bn2m = (const float*)d_in[10];
    const float* bn2v = (const float*)d_in[11];
    const float* sa1_w3 = (const float*)d_in[12];
    const float* bn3g = (const float*)d_in[13];
    const float* bn3b = (const float*)d_in[14];
    const float* bn3m = (const float*)d_in[15];
    const float* bn3v = (const float*)d_in[16];
    const float* att1w = (const float*)d_in[17];
    const float* att1b = (const float*)d_in[18];
    const float* sa3_w1 = (const float*)d_in[19];
    const float* s1g = (const float*)d_in[20];
    const float* s1b = (const float*)d_in[21];
    const float* s1m = (const float*)d_in[22];
    const float* s1v = (const float*)d_in[23];
    const float* sa3_w2 = (const float*)d_in[24];
    const float* s2g = (const float*)d_in[25];
    const float* s2b = (const float*)d_in[26];
    const float* s2m = (const float*)d_in[27];
    const float* s2v = (const float*)d_in[28];
    const float* sa3_w3 = (const float*)d_in[29];
    const float* s3g = (const float*)d_in[30];
    const float* s3b = (const float*)d_in[31];
    const float* s3m = (const float*)d_in[32];
    const float* s3v = (const float*)d_in[33];
    const float* att3w = (const float*)d_in[34];
    const float* fc1w = (const float*)d_in[35];
    const float* h1g = (const float*)d_in[36];
    const float* h1b = (const float*)d_in[37];
    const float* h1m = (const float*)d_in[38];
    const float* h1v = (const float*)d_in[39];
    const float* fc2w = (const float*)d_in[40];
    const float* h2g = (const float*)d_in[41];
    const float* h2b = (const float*)d_in[42];
    const float* h2m = (const float*)d_in[43];
    const float* h2v = (const float*)d_in[44];
    const float* predw = (const float*)d_in[45];
    const float* predb = (const float*)d_in[46];
    float* out = (float*)d_out;

    // ---- workspace: small linear region, then overlaid big region ----
    char* wsb = (char*)d_ws;
    size_t off = 0;
    auto alloc = [&](size_t bytes) -> void* {
        off = (off + 255) & ~(size_t)255;
        void* p = wsb + off;
        off += bytes;
        return p;
    };
    ushort* Wt2 = (ushort*)alloc(128 * 64 * 2);
    ushort* Wt3 = (ushort*)alloc(256 * 128 * 2);
    ushort* WtS1 = (ushort*)alloc(256 * 288 * 2);
    ushort* WtS2 = (ushort*)alloc(512 * 256 * 2);
    ushort* WtS3 = (ushort*)alloc(1024 * 512 * 2);
    float* sc2 = (float*)alloc(128 * 4);  float* sh2 = (float*)alloc(128 * 4);
    float* sc3 = (float*)alloc(256 * 4);  float* sh3 = (float*)alloc(256 * 4);
    float* scS1 = (float*)alloc(256 * 4); float* shS1 = (float*)alloc(256 * 4);
    float* scS2 = (float*)alloc(512 * 4); float* shS2 = (float*)alloc(512 * 4);
    float* scS3 = (float*)alloc(1024 * 4); float* shS3 = (float*)alloc(1024 * 4);
    float* logitsP = (float*)alloc((size_t)16 * M_ROWS * 4);  // 4 MB partials
    float* alpha = (float*)alloc((size_t)M_ROWS * 4);
    float* pooled = (float*)alloc(16 * 1024 * 4);
    float* h1buf = (float*)alloc(16 * 512 * 4);
    float* h2buf = (float*)alloc(16 * 256 * 4);

    // big region, overlaid by live range.
    off = (off + MB - 1) & ~(MB - 1);
    char* bigA = wsb + off;            // 128 MB
    char* bigB = bigA + 128 * MB;      // 64 MB
    ushort* f1 = (ushort*)(bigA);             //  8 MB  [L1, G2)
    ushort* f2 = (ushort*)(bigA + 8 * MB);    // 16 MB  [G2, G3)
    ushort* f3 = (ushort*)(bigA + 24 * MB);   // 32 MB  [G3, gate)
    ushort* G  = (ushort*)(bigA + 56 * MB);   // 36 MB  [gate, S1)
    ushort* g1 = (ushort*)(bigA + 92 * MB);   // 32 MB  [S1, S2)
    ushort* g3 = (ushort*)(bigA);             // 128 MB [S3, pool)
    ushort* g2 = (ushort*)(bigB);             // 64 MB  [S2, S3)

    // ---- prep ----
    PrepArgs pa;
    const float* wsrcs[5] = {sa1_w2, sa1_w3, sa3_w1, sa3_w2, sa3_w3};
    ushort* wdsts[5] = {Wt2, Wt3, WtS1, WtS2, WtS3};
    int wKs[5] = {64, 128, 259, 256, 512};
    int wNs[5] = {128, 256, 256, 512, 1024};
    int wKps[5] = {64, 128, 288, 256, 512};
    const float* gs[5] = {bn2g, bn3g, s1g, s2g, s3g};
    const float* bbs[5] = {bn2b, bn3b, s1b, s2b, s3b};
    const float* mms[5] = {bn2m, bn3m, s1m, s2m, s3m};
    const float* vvs[5] = {bn2v, bn3v, s1v, s2v, s3v};
    float* scs[5] = {sc2, sc3, scS1, scS2, scS3};
    float* shs[5] = {sh2, sh3, shS1, shS2, shS3};
    int Cs[5] = {128, 256, 256, 512, 1024};
    int totalW = 0, totalC = 0;
    for (int i = 0; i < 5; ++i) {
        pa.wsrc[i] = wsrcs[i]; pa.wdst[i] = wdsts[i];
        pa.wK[i] = wKs[i]; pa.wN[i] = wNs[i]; pa.wKp[i] = wKps[i];
        pa.wcount[i] = wNs[i] * wKps[i];
        totalW += pa.wcount[i];
        pa.g[i] = gs[i]; pa.bb[i] = bbs[i]; pa.mm[i] = mms[i]; pa.vv[i] = vvs[i];
        pa.sc[i] = scs[i]; pa.sh[i] = shs[i]; pa.C[i] = Cs[i];
        totalC += Cs[i];
    }
    int prepBlocks = (totalW + totalC + 255) / 256;
    prep_kernel<<<prepBlocks, 256, 0, stream>>>(pa, totalW, totalC);
    zero_kernel<<<(16 * 1024 + 255) / 256, 256, 0, stream>>>(pooled, 16 * 1024);

    // ---- layer 1 ----
    l1_kernel<<<M_ROWS / 4, 256, 0, stream>>>(xyz, pts, sa1_w1, bn1g, bn1b, bn1m, bn1v, f1);
    // ---- layers 2,3 ----
    gemm_bn_relu<<<512 * 1, 256, 0, stream>>>(f1, Wt2, sc2, sh2, f2, 128, 64, 1, nullptr, nullptr);
    gemm_bn_relu<<<512 * 2, 256, 0, stream>>>(f2, Wt3, sc3, sh3, f3, 256, 128, 2, nullptr, nullptr);
    // ---- gate + concat ----
    gate_kernel<<<M_ROWS / 4, 256, 0, stream>>>(f3, att1w, att1b, xyz, G);
    // ---- SA3 ----
    gemm_bn_relu<<<512 * 2, 256, 0, stream>>>(G, WtS1, scS1, shS1, g1, 256, 288, 2, nullptr, nullptr);
    gemm_bn_relu<<<512 * 4, 256, 0, stream>>>(g1, WtS2, scS2, shS2, g2, 512, 256, 4, nullptr, nullptr);
    // S3: fused attention-logits partial slices (no atomics)
    gemm_bn_relu<<<512 * 8, 256, 0, stream>>>(g2, WtS3, scS3, shS3, g3, 1024, 512, 8, att3w, logitsP);
    // ---- attention pooling ----
    softmax_kernel<<<16, 1024, 0, stream>>>(logitsP, alpha);
    pool_kernel<<<dim3(1, 16, 16), 256, 0, stream>>>(g3, alpha, pooled);
    // ---- head ----
    head1_kernel<<<32, 256, 0, stream>>>(pooled, fc1w, h1g, h1b, h1m, h1v, h1buf);
    head2_kernel<<<16, 256, 0, stream>>>(h1buf, fc2w, h2g, h2b, h2m, h2v, h2buf);
    head3_kernel<<<16, 64, 0, stream>>>(h2buf, predw, predb, out);
}

// Round 5
// 444.828 us; speedup vs baseline: 1.1552x; 1.0526x over previous
//
#include <hip/hip_runtime.h>

// ---------------------------------------------------------------------------
// PointNet2-AT inference pipeline, bf16 MFMA GEMMs + fp32 epilogues.
// B=16, N=4096 -> M = 65536 rows everywhere.
// R1: live-range-overlaid workspace. R2: m97-style GEMM (global_load_lds 16B).
// R4: XCD-aware swizzle (FETCH 265->48MB) + logits partial slices.
// R4 post-mortem: S3 not BW-bound (1.35TB/s); ~1300cyc/K-iter vs 310 MFMA
//     floor: per-iter barrier drain + 8-way LDS bank conflicts (8.4e6).
// R5: BK=64 (half the drains), XOR bank-deswizzle on staging/ds_read
//     (conflict-free), S1 K padded 259->320.
// ---------------------------------------------------------------------------

#define M_ROWS 65536
#define MB ((size_t)1 << 20)

typedef __bf16 bf16x8 __attribute__((ext_vector_type(8)));
typedef float floatx4 __attribute__((ext_vector_type(4)));

__device__ __forceinline__ float b2f(ushort u) {
    unsigned int x = ((unsigned int)u) << 16;
    float f;
    __builtin_memcpy(&f, &x, 4);
    return f;
}
__device__ __forceinline__ ushort f2bf(float f) {
    unsigned int x;
    __builtin_memcpy(&x, &f, 4);
    unsigned int r = x + 0x7fffu + ((x >> 16) & 1u);  // RNE
    return (ushort)(r >> 16);
}

// async global->LDS, 16B per lane; LDS dest = wave-uniform base + lane*16
__device__ __forceinline__ void gl_lds16(const ushort* g, ushort* l) {
    __builtin_amdgcn_global_load_lds(
        (const __attribute__((address_space(1))) unsigned int*)g,
        (__attribute__((address_space(3))) unsigned int*)l, 16, 0, 0);
}

// ---------------------------------------------------------------------------
// Prep: transpose+convert weights fp32[K,N] -> bf16 Wt[N,Kp] (zero-padded K),
// and fold BN params into scale/shift arrays.
// ---------------------------------------------------------------------------
struct PrepArgs {
    const float* wsrc[5]; ushort* wdst[5]; int wK[5], wN[5], wKp[5], wcount[5];
    const float* g[5]; const float* bb[5]; const float* mm[5]; const float* vv[5];
    float* sc[5]; float* sh[5]; int C[5];
};

__global__ __launch_bounds__(256) void prep_kernel(PrepArgs p, int totalW, int totalC) {
    int idx = blockIdx.x * 256 + threadIdx.x;
    if (idx < totalW) {
        int s = 0, base = 0;
        for (s = 0; s < 5; ++s) {
            if (idx < base + p.wcount[s]) break;
            base += p.wcount[s];
        }
        int local = idx - base;
        int n = local / p.wKp[s];
        int k = local - n * p.wKp[s];
        p.wdst[s][local] = (k < p.wK[s]) ? f2bf(p.wsrc[s][k * p.wN[s] + n]) : (ushort)0;
    } else {
        int cidx = idx - totalW;
        if (cidx < totalC) {
            int s = 0, base = 0;
            for (s = 0; s < 5; ++s) {
                if (cidx < base + p.C[s]) break;
                base += p.C[s];
            }
            int c = cidx - base;
            float scv = p.g[s][c] * rsqrtf(p.vv[s][c] + 1e-5f);
            p.sc[s][c] = scv;
            p.sh[s][c] = p.bb[s][c] - p.mm[s][c] * scv;
        }
    }
}

__global__ __launch_bounds__(256) void zero_kernel(float* __restrict__ p, int n) {
    int i = blockIdx.x * 256 + threadIdx.x;
    if (i < n) p[i] = 0.0f;
}

// ---------------------------------------------------------------------------
// Layer 1: [M,6] @ [6,64] + BN + ReLU -> bf16 [M,64].  (K=6: vector kernel)
// ---------------------------------------------------------------------------
__global__ __launch_bounds__(256) void l1_kernel(
    const float* __restrict__ xyz, const float* __restrict__ pts,
    const float* __restrict__ w1, const float* __restrict__ g,
    const float* __restrict__ b, const float* __restrict__ m,
    const float* __restrict__ v, ushort* __restrict__ f1) {
    __shared__ float w[384];
    __shared__ float sc[64], sh[64];
    int tid = threadIdx.x;
    if (tid < 64) {
        float s = g[tid] * rsqrtf(v[tid] + 1e-5f);
        sc[tid] = s;
        sh[tid] = b[tid] - m[tid] * s;
    }
    for (int i = tid; i < 384; i += 256) w[i] = w1[i];
    __syncthreads();
    int r = blockIdx.x * 4 + (tid >> 6);
    int c = tid & 63;
    float x0 = xyz[r * 3], x1 = xyz[r * 3 + 1], x2 = xyz[r * 3 + 2];
    float p0 = pts[r * 3], p1 = pts[r * 3 + 1], p2 = pts[r * 3 + 2];
    float a = x0 * w[c] + x1 * w[64 + c] + x2 * w[128 + c] +
              p0 * w[192 + c] + p1 * w[256 + c] + p2 * w[320 + c];
    a = fmaxf(a * sc[c] + sh[c], 0.0f);
    f1[(size_t)r * 64 + c] = f2bf(a);
}

// ---------------------------------------------------------------------------
// GEMM: C[M,N] = ReLU(BN(A[M,K] @ W[K,N])), A bf16 [M,K], Wt bf16 [N,K].
// Grid: 1D, XCD-swizzled: L = chunk*(8*numN) + nt*8 + xcd; m = chunk*8 + xcd.
// 128x128 tile, BK=64, 4 waves x (4x4) 16x16x32 MFMA (2 K-halves per iter).
// global_load_lds(16B) into LDS [128][64] with XOR block swizzle:
//   global 16B-block b of row r lives at LDS slot (b ^ (r&7)) -> conflict-free
//   ds_read_b128 (bank-quad = 4*slot mod 32, row term drops out at 128B stride)
// Fused logits (S3): partial dot over wave-col's 64 cols -> slice nt*2+wc.
// K % 64 == 0 required.
// ---------------------------------------------------------------------------
__global__ __launch_bounds__(256) void gemm_bn_relu(
    const ushort* __restrict__ A, const ushort* __restrict__ Wt,
    const float* __restrict__ scale, const float* __restrict__ shift,
    ushort* __restrict__ C, int N, int K, int numN,
    const float* __restrict__ attw, float* __restrict__ logitsP) {
    __shared__ ushort As[128 * 64];
    __shared__ ushort Bs[128 * 64];
    const int tid = threadIdx.x;
    const int g8 = numN * 8;
    const int chunk = blockIdx.x / g8;
    const int rem = blockIdx.x - chunk * g8;
    const int nt = rem >> 3;
    const int xcd = rem & 7;
    const int bn0 = nt * 128;
    const int bm0 = (chunk * 8 + xcd) * 128;

    const int wid = tid >> 6, ln = tid & 63;
    const int wr = wid >> 1, wc = wid & 1;
    const int lm = ln & 15, q = ln >> 4;
    const int sx = lm & 7;  // fragment-read XOR key (row_a&7 == lm&7)

    floatx4 acc[4][4];
#pragma unroll
    for (int i = 0; i < 4; ++i)
#pragma unroll
        for (int j = 0; j < 4; ++j) acc[i][j] = (floatx4){0.f, 0.f, 0.f, 0.f};

    // staging lane mapping: per call covers 32 rows x 8 16B-blocks
    const int srow = tid >> 3;            // 0..31 (row within 32-row slab)
    const int sb = tid & 7;               // LDS dest block
    const int sgb = sb ^ (srow & 7);      // global source block (XOR swizzle)
    const ushort* aP[4];
    const ushort* bP[4];
#pragma unroll
    for (int l = 0; l < 4; ++l) {
        int row = l * 32 + srow;
        aP[l] = &A[(size_t)(bm0 + row) * K + (sgb << 3)];
        bP[l] = &Wt[(size_t)(bn0 + row) * K + (sgb << 3)];
    }
    ushort* aL = &As[wid * 512];  // wave-uniform; + l*2048 per slab
    ushort* bL = &Bs[wid * 512];

    for (int kt = 0; kt < K; kt += 64) {
#pragma unroll
        for (int l = 0; l < 4; ++l) gl_lds16(aP[l], aL + l * 2048);
#pragma unroll
        for (int l = 0; l < 4; ++l) gl_lds16(bP[l], bL + l * 2048);
#pragma unroll
        for (int l = 0; l < 4; ++l) { aP[l] += 64; bP[l] += 64; }
        asm volatile("s_waitcnt vmcnt(0)" ::: "memory");
        __syncthreads();
#pragma unroll
        for (int h = 0; h < 2; ++h) {
            const int slot = ((h << 2) | q) ^ sx;  // lane-constant
            bf16x8 af[4], bf[4];
#pragma unroll
            for (int i = 0; i < 4; ++i)
                af[i] = *(const bf16x8*)(&As[(wr * 64 + i * 16 + lm) * 64 + (slot << 3)]);
#pragma unroll
            for (int i = 0; i < 4; ++i)
                bf[i] = *(const bf16x8*)(&Bs[(wc * 64 + i * 16 + lm) * 64 + (slot << 3)]);
#pragma unroll
            for (int mi = 0; mi < 4; ++mi)
#pragma unroll
                for (int ni = 0; ni < 4; ++ni)
                    acc[mi][ni] = __builtin_amdgcn_mfma_f32_16x16x32_bf16(
                        af[mi], bf[ni], acc[mi][ni], 0, 0, 0);
        }
        __syncthreads();
    }

    float s[4], t[4], aw[4];
#pragma unroll
    for (int ni = 0; ni < 4; ++ni) {
        int gcol = bn0 + wc * 64 + ni * 16 + lm;
        s[ni] = scale[gcol];
        t[ni] = shift[gcol];
        aw[ni] = attw ? attw[gcol] : 0.0f;
    }
#pragma unroll
    for (int mi = 0; mi < 4; ++mi) {
        int grow0 = bm0 + wr * 64 + mi * 16 + q * 4;
#pragma unroll
        for (int r = 0; r < 4; ++r) {
            float p = 0.0f;
#pragma unroll
            for (int ni = 0; ni < 4; ++ni) {
                int gcol = bn0 + wc * 64 + ni * 16 + lm;
                float val = fmaxf(acc[mi][ni][r] * s[ni] + t[ni], 0.0f);
                C[(size_t)(grow0 + r) * N + gcol] = f2bf(val);
                p += val * aw[ni];
            }
            if (logitsP) {
#pragma unroll
                for (int o = 8; o > 0; o >>= 1) p += __shfl_xor(p, o, 16);
                if (lm == 0)
                    logitsP[(size_t)(nt * 2 + wc) * M_ROWS + grow0 + r] = p;
            }
        }
    }
}

// ---------------------------------------------------------------------------
// Gate: s = sigmoid(f3 . att_w + att_b); G = [bf16(xyz), f3*s, 0pad] [M,320]
// ---------------------------------------------------------------------------
__global__ __launch_bounds__(256) void gate_kernel(
    const ushort* __restrict__ f3, const float* __restrict__ attw,
    const float* __restrict__ attb, const float* __restrict__ xyz,
    ushort* __restrict__ G) {
    int tid = threadIdx.x;
    int ln = tid & 63, wid = tid >> 6;
    int r = blockIdx.x * 4 + wid;
    ushort4 fv = *(const ushort4*)&f3[(size_t)r * 256 + ln * 4];
    float f0 = b2f(fv.x), f1 = b2f(fv.y), f2 = b2f(fv.z), f3v = b2f(fv.w);
    float4 aw = *(const float4*)&attw[ln * 4];
    float sum = f0 * aw.x + f1 * aw.y + f2 * aw.z + f3v * aw.w;
#pragma unroll
    for (int o = 32; o > 0; o >>= 1) sum += __shfl_xor(sum, o);
    float s = 1.0f / (1.0f + expf(-(sum + attb[0])));
    size_t gb = (size_t)r * 320;
    G[gb + 3 + ln * 4 + 0] = f2bf(f0 * s);
    G[gb + 3 + ln * 4 + 1] = f2bf(f1 * s);
    G[gb + 3 + ln * 4 + 2] = f2bf(f2 * s);
    G[gb + 3 + ln * 4 + 3] = f2bf(f3v * s);
    if (ln < 3) G[gb + ln] = f2bf(xyz[r * 3 + ln]);
    if (ln >= 3) G[gb + 256 + ln] = 0;  // cols 259..319 zero pad
}

// ---------------------------------------------------------------------------
// Softmax over N=4096 per batch (logits = sum of 16 partial slices).
// ---------------------------------------------------------------------------
__global__ __launch_bounds__(1024) void softmax_kernel(
    const float* __restrict__ logitsP, float* __restrict__ alpha) {
    __shared__ float red[1024];
    int b = blockIdx.x, t = threadIdx.x;
    float4 v = (float4){0.f, 0.f, 0.f, 0.f};
#pragma unroll
    for (int j = 0; j < 16; ++j) {
        float4 pv = *(const float4*)&logitsP[(size_t)j * M_ROWS + b * 4096 + t * 4];
        v.x += pv.x; v.y += pv.y; v.z += pv.z; v.w += pv.w;
    }
    float mx = fmaxf(fmaxf(v.x, v.y), fmaxf(v.z, v.w));
    red[t] = mx;
    __syncthreads();
    for (int s = 512; s > 0; s >>= 1) {
        if (t < s) red[t] = fmaxf(red[t], red[t + s]);
        __syncthreads();
    }
    float M = red[0];
    __syncthreads();
    float e0 = expf(v.x - M), e1 = expf(v.y - M), e2 = expf(v.z - M), e3 = expf(v.w - M);
    red[t] = e0 + e1 + e2 + e3;
    __syncthreads();
    for (int s = 512; s > 0; s >>= 1) {
        if (t < s) red[t] += red[t + s];
        __syncthreads();
    }
    float inv = 1.0f / red[0];
    *(float4*)&alpha[b * 4096 + t * 4] = make_float4(e0 * inv, e1 * inv, e2 * inv, e3 * inv);
}

// ---------------------------------------------------------------------------
// Pool: pooled[b,c] = sum_n alpha[b,n]*g3[b,n,c]; each thread: 4 cols (ushort4)
// ---------------------------------------------------------------------------
__global__ __launch_bounds__(256) void pool_kernel(
    const ushort* __restrict__ g3, const float* __restrict__ alpha,
    float* __restrict__ pooled) {
    int c4 = threadIdx.x * 4;
    int b = blockIdx.y;
    int n0 = blockIdx.z * 256;
    const ushort* base = g3 + ((size_t)b * 4096 + n0) * 1024 + c4;
    const float* al = alpha + b * 4096 + n0;
    float a0 = 0.f, a1 = 0.f, a2 = 0.f, a3 = 0.f;
#pragma unroll 4
    for (int n = 0; n < 256; ++n) {
        float w = al[n];
        ushort4 gv = *(const ushort4*)&base[(size_t)n * 1024];
        a0 += w * b2f(gv.x); a1 += w * b2f(gv.y);
        a2 += w * b2f(gv.z); a3 += w * b2f(gv.w);
    }
    float* pd = &pooled[b * 1024 + c4];
    atomicAdd(pd + 0, a0); atomicAdd(pd + 1, a1);
    atomicAdd(pd + 2, a2); atomicAdd(pd + 3, a3);
}

// ---------------------------------------------------------------------------
// Head
// ---------------------------------------------------------------------------
__global__ __launch_bounds__(256) void head1_kernel(
    const float* __restrict__ pooled, const float* __restrict__ w,
    const float* __restrict__ g, const float* __restrict__ bb,
    const float* __restrict__ m, const float* __restrict__ v,
    float* __restrict__ h1) {
    int idx = blockIdx.x * 256 + threadIdx.x;  // 16*512
    int b = idx >> 9, c = idx & 511;
    float sc = g[c] * rsqrtf(v[c] + 1e-5f);
    float sh = bb[c] - m[c] * sc;
    const float* pr = pooled + b * 1024;
    float acc = 0.0f;
    for (int k = 0; k < 1024; ++k) acc += pr[k] * w[k * 512 + c];
    h1[idx] = fmaxf(acc * sc + sh, 0.0f);
}

__global__ __launch_bounds__(256) void head2_kernel(
    const float* __restrict__ h1, const float* __restrict__ w,
    const float* __restrict__ g, const float* __restrict__ bb,
    const float* __restrict__ m, const float* __restrict__ v,
    float* __restrict__ h2) {
    int b = blockIdx.x, c = threadIdx.x;  // 16 x 256
    float sc = g[c] * rsqrtf(v[c] + 1e-5f);
    float sh = bb[c] - m[c] * sc;
    const float* hr = h1 + b * 512;
    float acc = 0.0f;
    for (int k = 0; k < 512; ++k) acc += hr[k] * w[k * 256 + c];
    h2[b * 256 + c] = fmaxf(acc * sc + sh, 0.0f);
}

__global__ __launch_bounds__(64) void head3_kernel(
    const float* __restrict__ h2, const float* __restrict__ pw,
    const float* __restrict__ pb, float* __restrict__ out) {
    int b = blockIdx.x, ln = threadIdx.x;
    float4 hv = *(const float4*)&h2[b * 256 + ln * 4];
    float4 wv = *(const float4*)&pw[ln * 4];
    float sum = hv.x * wv.x + hv.y * wv.y + hv.z * wv.z + hv.w * wv.w;
#pragma unroll
    for (int o = 32; o > 0; o >>= 1) sum += __shfl_xor(sum, o);
    if (ln == 0) out[b] = sum + pb[0];
}

// ---------------------------------------------------------------------------
extern "C" void kernel_launch(void* const* d_in, const int* in_sizes, int n_in,
                              void* d_out, int out_size, void* d_ws, size_t ws_size,
                              hipStream_t stream) {
    (void)in_sizes; (void)n_in; (void)out_size; (void)ws_size;
    const float* xyz = (const float*)d_in[0];
    const float* pts = (const float*)d_in[1];
    const float* sa1_w1 = (const float*)d_in[2];
    const float* bn1g = (const float*)d_in[3];
    const float* bn1b = (const float*)d_in[4];
    const float* bn1m = (const float*)d_in[5];
    const float* bn1v = (const float*)d_in[6];
    const float* sa1_w2 = (const float*)d_in[7];
    const float* bn2g = (const float*)d_in[8];
    const float* bn2b = (const float*)d_in[9];
    const float* bn2m = (const float*)d_in[10];
    const float* bn2v = (const float*)d_in[11];
    const float* sa1_w3 = (const float*)d_in[12];
    const float* bn3g = (const float*)d_in[13];
    const float* bn3b = (const float*)d_in[14];
    const float* bn3m = (const float*)d_in[15];
    const float* bn3v = (const float*)d_in[16];
    const float* att1w = (const float*)d_in[17];
    const float* att1b = (const float*)d_in[18];
    const float* sa3_w1 = (const float*)d_in[19];
    const float* s1g = (const float*)d_in[20];
    const float* s1b = (const float*)d_in[21];
    const float* s1m = (const float*)d_in[22];
    const float* s1v = (const float*)d_in[23];
    const float* sa3_w2 = (const float*)d_in[24];
    const float* s2g = (const float*)d_in[25];
    const float* s2b = (const float*)d_in[26];
    const float* s2m = (const float*)d_in[27];
    const float* s2v = (const float*)d_in[28];
    const float* sa3_w3 = (const float*)d_in[29];
    const float* s3g = (const float*)d_in[30];
    const float* s3b = (const float*)d_in[31];
    const float* s3m = (const float*)d_in[32];
    const float* s3v = (const float*)d_in[33];
    const float* att3w = (const float*)d_in[34];
    const float* fc1w = (const float*)d_in[35];
    const float* h1g = (const float*)d_in[36];
    const float* h1b = (const float*)d_in[37];
    const float* h1m = (const float*)d_in[38];
    const float* h1v = (const float*)d_in[39];
    const float* fc2w = (const float*)d_in[40];
    const float* h2g = (const float*)d_in[41];
    const float* h2b = (const float*)d_in[42];
    const float* h2m = (const float*)d_in[43];
    const float* h2v = (const float*)d_in[44];
    const float* predw = (const float*)d_in[45];
    const float* predb = (const float*)d_in[46];
    float* out = (float*)d_out;

    // ---- workspace: small linear region, then overlaid big region ----
    char* wsb = (char*)d_ws;
    size_t off = 0;
    auto alloc = [&](size_t bytes) -> void* {
        off = (off + 255) & ~(size_t)255;
        void* p = wsb + off;
        off += bytes;
        return p;
    };
    ushort* Wt2 = (ushort*)alloc(128 * 64 * 2);
    ushort* Wt3 = (ushort*)alloc(256 * 128 * 2);
    ushort* WtS1 = (ushort*)alloc(256 * 320 * 2);
    ushort* WtS2 = (ushort*)alloc(512 * 256 * 2);
    ushort* WtS3 = (ushort*)alloc(1024 * 512 * 2);
    float* sc2 = (float*)alloc(128 * 4);  float* sh2 = (float*)alloc(128 * 4);
    float* sc3 = (float*)alloc(256 * 4);  float* sh3 = (float*)alloc(256 * 4);
    float* scS1 = (float*)alloc(256 * 4); float* shS1 = (float*)alloc(256 * 4);
    float* scS2 = (float*)alloc(512 * 4); float* shS2 = (float*)alloc(512 * 4);
    float* scS3 = (float*)alloc(1024 * 4); float* shS3 = (float*)alloc(1024 * 4);
    float* logitsP = (float*)alloc((size_t)16 * M_ROWS * 4);  // 4 MB partials
    float* alpha = (float*)alloc((size_t)M_ROWS * 4);
    float* pooled = (float*)alloc(16 * 1024 * 4);
    float* h1buf = (float*)alloc(16 * 512 * 4);
    float* h2buf = (float*)alloc(16 * 256 * 4);

    // big region, overlaid by live range (G now [M,320] = 40 MB).
    off = (off + MB - 1) & ~(MB - 1);
    char* bigA = wsb + off;            // 128 MB
    char* bigB = bigA + 128 * MB;      // 64 MB
    ushort* f1 = (ushort*)(bigA);             //  8 MB  [L1, G2)
    ushort* f2 = (ushort*)(bigA + 8 * MB);    // 16 MB  [G2, G3)
    ushort* f3 = (ushort*)(bigA + 24 * MB);   // 32 MB  [G3, gate)
    ushort* G  = (ushort*)(bigA + 56 * MB);   // 40 MB  [gate, S1)
    ushort* g1 = (ushort*)(bigA + 96 * MB);   // 32 MB  [S1, S2)
    ushort* g3 = (ushort*)(bigA);             // 128 MB [S3, pool)
    ushort* g2 = (ushort*)(bigB);             // 64 MB  [S2, S3)

    // ---- prep ----
    PrepArgs pa;
    const float* wsrcs[5] = {sa1_w2, sa1_w3, sa3_w1, sa3_w2, sa3_w3};
    ushort* wdsts[5] = {Wt2, Wt3, WtS1, WtS2, WtS3};
    int wKs[5] = {64, 128, 259, 256, 512};
    int wNs[5] = {128, 256, 256, 512, 1024};
    int wKps[5] = {64, 128, 320, 256, 512};
    const float* gs[5] = {bn2g, bn3g, s1g, s2g, s3g};
    const float* bbs[5] = {bn2b, bn3b, s1b, s2b, s3b};
    const float* mms[5] = {bn2m, bn3m, s1m, s2m, s3m};
    const float* vvs[5] = {bn2v, bn3v, s1v, s2v, s3v};
    float* scs[5] = {sc2, sc3, scS1, scS2, scS3};
    float* shs[5] = {sh2, sh3, shS1, shS2, shS3};
    int Cs[5] = {128, 256, 256, 512, 1024};
    int totalW = 0, totalC = 0;
    for (int i = 0; i < 5; ++i) {
        pa.wsrc[i] = wsrcs[i]; pa.wdst[i] = wdsts[i];
        pa.wK[i] = wKs[i]; pa.wN[i] = wNs[i]; pa.wKp[i] = wKps[i];
        pa.wcount[i] = wNs[i] * wKps[i];
        totalW += pa.wcount[i];
        pa.g[i] = gs[i]; pa.bb[i] = bbs[i]; pa.mm[i] = mms[i]; pa.vv[i] = vvs[i];
        pa.sc[i] = scs[i]; pa.sh[i] = shs[i]; pa.C[i] = Cs[i];
        totalC += Cs[i];
    }
    int prepBlocks = (totalW + totalC + 255) / 256;
    prep_kernel<<<prepBlocks, 256, 0, stream>>>(pa, totalW, totalC);
    zero_kernel<<<(16 * 1024 + 255) / 256, 256, 0, stream>>>(pooled, 16 * 1024);

    // ---- layer 1 ----
    l1_kernel<<<M_ROWS / 4, 256, 0, stream>>>(xyz, pts, sa1_w1, bn1g, bn1b, bn1m, bn1v, f1);
    // ---- layers 2,3 ----
    gemm_bn_relu<<<512 * 1, 256, 0, stream>>>(f1, Wt2, sc2, sh2, f2, 128, 64, 1, nullptr, nullptr);
    gemm_bn_relu<<<512 * 2, 256, 0, stream>>>(f2, Wt3, sc3, sh3, f3, 256, 128, 2, nullptr, nullptr);
    // ---- gate + concat (G stride 320, K-padded) ----
    gate_kernel<<<M_ROWS / 4, 256, 0, stream>>>(f3, att1w, att1b, xyz, G);
    // ---- SA3 ----
    gemm_bn_relu<<<512 * 2, 256, 0, stream>>>(G, WtS1, scS1, shS1, g1, 256, 320, 2, nullptr, nullptr);
    gemm_bn_relu<<<512 * 4, 256, 0, stream>>>(g1, WtS2, scS2, shS2, g2, 512, 256, 4, nullptr, nullptr);
    // S3: fused attention-logits partial slices (no atomics)
    gemm_bn_relu<<<512 * 8, 256, 0, stream>>>(g2, WtS3, scS3, shS3, g3, 1024, 512, 8, att3w, logitsP);
    // ---- attention pooling ----
    softmax_kernel<<<16, 1024, 0, stream>>>(logitsP, alpha);
    pool_kernel<<<dim3(1, 16, 16), 256, 0, stream>>>(g3, alpha, pooled);
    // ---- head ----
    head1_kernel<<<32, 256, 0, stream>>>(pooled, fc1w, h1g, h1b, h1m, h1v, h1buf);
    head2_kernel<<<16, 256, 0, stream>>>(h1buf, fc2w, h2g, h2b, h2m, h2v, h2buf);
    head3_kernel<<<16, 64, 0, stream>>>(h2buf, predw, predb, out);
}